// Round 1
// baseline (2598.627 us; speedup 1.0000x reference)
//
#include <hip/hip_runtime.h>
#include <math.h>

#define BB 4
#define SS 256
#define DD 300
#define EE 128
#define LL 20
#define H3 384
#define D2 256   // 2E
#define D12 1536 // 12E

__device__ __forceinline__ float sigmoidf_(float x){ return 1.f/(1.f+expf(-x)); }

// ---------------- embedding gather ----------------
__global__ void k_embed(const int* __restrict__ inp, const float* __restrict__ emb,
                        float* __restrict__ x){
  int row = blockIdx.x;            // b*S+s
  int idx = inp[row];
  const float* src = emb + (size_t)idx*DD;
  float* dst = x + (size_t)row*DD;
  for (int d=threadIdx.x; d<DD; d+=blockDim.x) dst[d]=src[d];
}

// ---------------- generic matmul: out[M,N] = X[M,K] @ W[N,K]^T + bias ----------------
__global__ __launch_bounds__(256) void k_matmul(const float* __restrict__ X, const float* __restrict__ W,
                        const float* __restrict__ bias, float* __restrict__ out,
                        int M, int N, int K){
  __shared__ __align__(16) float Xs[16][68];   // [kk][m]
  __shared__ __align__(16) float Ws[16][68];   // [kk][n]
  int tid=threadIdx.x, tx=tid&15, ty=tid>>4;
  int m0=blockIdx.y*64, n0=blockIdx.x*64;
  float acc[4][4]={};
  for (int k0=0;k0<K;k0+=16){
    #pragma unroll
    for (int i=0;i<4;i++){
      int idx=tid+i*256; int r=idx>>4, kk=idx&15; int gk=k0+kk;
      int gm=m0+r; Xs[kk][r] = (gm<M && gk<K)? X[(size_t)gm*K+gk] : 0.f;
      int gn=n0+r; Ws[kk][r] = (gn<N && gk<K)? W[(size_t)gn*K+gk] : 0.f;
    }
    __syncthreads();
    #pragma unroll
    for (int kk=0;kk<16;kk++){
      float4 a=*(const float4*)&Xs[kk][ty*4];
      float4 b=*(const float4*)&Ws[kk][tx*4];
      float av[4]={a.x,a.y,a.z,a.w};
      float bv[4]={b.x,b.y,b.z,b.w};
      #pragma unroll
      for (int i=0;i<4;i++)
        #pragma unroll
        for (int j=0;j<4;j++) acc[i][j] += av[i]*bv[j];
    }
    __syncthreads();
  }
  #pragma unroll
  for (int i=0;i<4;i++){
    int gm=m0+ty*4+i; if (gm>=M) continue;
    #pragma unroll
    for (int j=0;j<4;j++){
      int gn=n0+tx*4+j; if (gn>=N) continue;
      out[(size_t)gm*N+gn] = acc[i][j] + (bias? bias[gn]:0.f);
    }
  }
}

// ---------------- GRU scan (one block per (batch, direction)) ----------------
__global__ __launch_bounds__(384) void k_gru_scan(const float* __restrict__ gxf, const float* __restrict__ gxb,
                          const float* __restrict__ whhf, const float* __restrict__ whhb,
                          const float* __restrict__ bhhf, const float* __restrict__ bhhb,
                          const float* __restrict__ h0,   // [2,B,E] or null
                          float* __restrict__ out,        // [B,S,2E]
                          float* __restrict__ hT){        // [2,B,E] or null
  int b=blockIdx.x, dir=blockIdx.y, tid=threadIdx.x;
  const float* gx  = dir? gxb : gxf;
  const float* whh = dir? whhb : whhf;
  const float* bhh = dir? bhhb : bhhf;
  float wrow[EE];                           // whh row cached in VGPRs
  #pragma unroll
  for (int i=0;i<EE;i++) wrow[i]=whh[(size_t)tid*EE+i];
  float brow=bhh[tid];
  __shared__ __align__(16) float h[EE];
  __shared__ float gh[H3];
  if (tid<EE) h[tid] = h0? h0[((size_t)dir*BB+b)*EE+tid] : 0.f;
  __syncthreads();
  for (int t=0;t<SS;t++){
    int s = dir? (SS-1-t) : t;
    float acc=brow;
    #pragma unroll
    for (int i=0;i<EE;i++) acc += wrow[i]*h[i];
    gh[tid]=acc;
    __syncthreads();
    if (tid<EE){
      const float* g = gx + ((size_t)b*SS+s)*H3;
      float r = sigmoidf_(g[tid]      + gh[tid]);
      float z = sigmoidf_(g[EE+tid]   + gh[EE+tid]);
      float n = tanhf(g[2*EE+tid] + r*gh[2*EE+tid]);
      float h2 = (1.f-z)*n + z*h[tid];
      h[tid]=h2;
      out[((size_t)b*SS+s)*D2 + dir*EE + tid] = h2;
    }
    __syncthreads();
  }
  if (hT && tid<EE) hT[((size_t)dir*BB+b)*EE+tid]=h[tid];
}

__global__ void k_copy_hq(const float* __restrict__ hq, float* __restrict__ agg){
  int row=blockIdx.x;
  agg[(size_t)row*D12 + threadIdx.x] = hq[(size_t)row*D2 + threadIdx.x];
}

// --------- block softmax over 256 values, p[tid] gets probability ---------
__device__ __forceinline__ void softmax256(float val, float* red, float* p){
  int tid=threadIdx.x;
  red[tid]=val; __syncthreads();
  for (int st=128; st>0; st>>=1){ if (tid<st) red[tid]=fmaxf(red[tid],red[tid+st]); __syncthreads(); }
  float mx=red[0]; __syncthreads();
  float ex=expf(val-mx); red[tid]=ex; __syncthreads();
  for (int st=128; st>0; st>>=1){ if (tid<st) red[tid]+=red[tid+st]; __syncthreads(); }
  float inv=1.f/red[0];
  p[tid]=ex*inv; __syncthreads();
}

// ---------------- additive-style attention (ptc: sign=+1, ptm: sign=-1) ----------------
__global__ __launch_bounds__(256) void k_attn_add(const float* __restrict__ A, const float* __restrict__ Bq,
                          const float* __restrict__ v, float sign,
                          const float* __restrict__ V, float* __restrict__ aggout, int off){
  __shared__ __align__(16) float bq[EE];
  __shared__ __align__(16) float vv[EE];
  __shared__ float p[SS]; __shared__ float red[SS];
  int q=blockIdx.x, b=blockIdx.y, tid=threadIdx.x;
  if (tid<EE){ bq[tid]=sign*Bq[((size_t)b*SS+q)*EE+tid]; vv[tid]=v[tid]; }
  __syncthreads();
  const float* Ar = A + ((size_t)b*SS+tid)*EE;   // thread = key index k
  float s=0.f;
  #pragma unroll
  for (int e=0;e<EE;e+=4){
    float4 a=*(const float4*)(Ar+e);
    float4 bb=*(const float4*)(bq+e);
    float4 vw=*(const float4*)(vv+e);
    s += vw.x*tanhf(a.x+bb.x)+vw.y*tanhf(a.y+bb.y)+vw.z*tanhf(a.z+bb.z)+vw.w*tanhf(a.w+bb.w);
  }
  softmax256(s, red, p);
  const float* V0 = V + (size_t)b*SS*D2;
  float o=0.f;
  for (int k=0;k<SS;k++) o += p[k]*V0[(size_t)k*D2+tid];
  aggout[((size_t)b*SS+q)*D12 + off + tid] = o;
}

// ---------------- bilinear attention (ptb) ----------------
__global__ __launch_bounds__(256) void k_attn_bil(const float* __restrict__ Pb, const float* __restrict__ hq,
                          const float* __restrict__ V, float* __restrict__ aggout, int off){
  __shared__ __align__(16) float hqq[D2];
  __shared__ float p[SS]; __shared__ float red[SS];
  int q=blockIdx.x, b=blockIdx.y, tid=threadIdx.x;
  hqq[tid]=hq[((size_t)b*SS+q)*D2+tid];
  __syncthreads();
  const float* Pr = Pb + ((size_t)b*SS+tid)*D2;
  float s=0.f;
  #pragma unroll
  for (int d=0;d<D2;d+=4){
    float4 a=*(const float4*)(Pr+d);
    float4 hh=*(const float4*)(hqq+d);
    s += a.x*hh.x+a.y*hh.y+a.z*hh.z+a.w*hh.w;
  }
  softmax256(s, red, p);
  const float* V0 = V + (size_t)b*SS*D2;
  float o=0.f;
  for (int k=0;k<SS;k++) o += p[k]*V0[(size_t)k*D2+tid];
  aggout[((size_t)b*SS+q)*D12 + off + tid] = o;
}

// ------- ptd/pts score: sc[b,q,k] = sum_e v[e] tanh( sum_d W[e,d] keys[b,k,d] qm[b,q,d] ) -------
// grid (4 m-tiles, S, B); 256 threads; per block 64 k x 128 e, 4x8 per thread.
__global__ __launch_bounds__(256) void k_mulattn_score(const float* __restrict__ keys, const float* __restrict__ qm,
                               const float* __restrict__ W, const float* __restrict__ v,
                               float* __restrict__ scbuf){
  __shared__ __align__(16) float XsT[16][68];    // [kk][m]  keyq chunk
  __shared__ __align__(16) float WsT[16][132];   // [kk][n]  W chunk
  __shared__ float hqq[D2];
  int m0=blockIdx.x*64, q=blockIdx.y, b=blockIdx.z;
  int tid=threadIdx.x, tx=tid&15, ty=tid>>4;
  hqq[tid]=qm[((size_t)b*SS+q)*D2+tid];
  __syncthreads();
  const float* kb = keys + (size_t)b*SS*D2;
  float acc[4][8]={};
  for (int d0=0; d0<D2; d0+=16){
    #pragma unroll
    for (int i=0;i<4;i++){
      int idx=tid+i*256; int m=idx>>4, kk=idx&15;
      XsT[kk][m]=kb[(size_t)(m0+m)*D2 + d0+kk]*hqq[d0+kk];
    }
    #pragma unroll
    for (int i=0;i<8;i++){
      int idx=tid+i*256; int n=idx>>4, kk=idx&15;
      WsT[kk][n]=W[(size_t)n*D2 + d0+kk];
    }
    __syncthreads();
    #pragma unroll
    for (int kk=0;kk<16;kk++){
      float4 a =*(const float4*)&XsT[kk][ty*4];
      float4 b0=*(const float4*)&WsT[kk][tx*8];
      float4 b1=*(const float4*)&WsT[kk][tx*8+4];
      float av[4]={a.x,a.y,a.z,a.w};
      float bv[8]={b0.x,b0.y,b0.z,b0.w,b1.x,b1.y,b1.z,b1.w};
      #pragma unroll
      for (int i=0;i<4;i++)
        #pragma unroll
        for (int j=0;j<8;j++) acc[i][j] += av[i]*bv[j];
    }
    __syncthreads();
  }
  float vreg[8];
  #pragma unroll
  for (int j=0;j<8;j++) vreg[j]=v[tx*8+j];
  #pragma unroll
  for (int i=0;i<4;i++){
    float s=0.f;
    #pragma unroll
    for (int j=0;j<8;j++) s += vreg[j]*tanhf(acc[i][j]);
    s += __shfl_xor(s,1,16);
    s += __shfl_xor(s,2,16);
    s += __shfl_xor(s,4,16);
    s += __shfl_xor(s,8,16);
    if (tx==0) scbuf[((size_t)b*SS+q)*SS + m0 + ty*4 + i] = s;
  }
}

// ---------------- softmax over precomputed scores + weighted value sum ----------------
__global__ __launch_bounds__(256) void k_softmax_pv(const float* __restrict__ scbuf, const float* __restrict__ V,
                            float* __restrict__ aggout, int off){
  __shared__ float p[SS]; __shared__ float red[SS];
  int q=blockIdx.x, b=blockIdx.y, tid=threadIdx.x;
  float val = scbuf[((size_t)b*SS+q)*SS + tid];
  softmax256(val, red, p);
  const float* V0 = V + (size_t)b*SS*D2;
  float o=0.f;
  for (int k=0;k<SS;k++) o += p[k]*V0[(size_t)k*D2+tid];
  aggout[((size_t)b*SS+q)*D12 + off + tid] = o;
}

// ---------------- rl pooling over hq ----------------
__global__ __launch_bounds__(256) void k_rl(const float* __restrict__ spj, const float* __restrict__ hq,
                    const float* __restrict__ vp, float* __restrict__ rl){
  __shared__ __align__(16) float vpl[EE];
  __shared__ float p[SS]; __shared__ float red[SS];
  int b=blockIdx.x, tid=threadIdx.x;
  if (tid<EE) vpl[tid]=vp[tid];
  __syncthreads();
  const float* row = spj + ((size_t)b*SS+tid)*EE;
  float sj=0.f;
  #pragma unroll
  for (int e=0;e<EE;e+=4){
    float4 a=*(const float4*)(row+e);
    float4 vw=*(const float4*)(vpl+e);
    sj += vw.x*tanhf(a.x)+vw.y*tanhf(a.y)+vw.z*tanhf(a.z)+vw.w*tanhf(a.w);
  }
  softmax256(sj, red, p);
  float o=0.f;
  for (int s=0;s<SS;s++) o += p[s]*hq[((size_t)b*SS+s)*D2+tid];
  rl[(size_t)b*D2+tid]=o;
}

// ---------------- final pooling + prediction ----------------
__global__ __launch_bounds__(256) void k_final(const float* __restrict__ sA, const float* __restrict__ sB,
                       const float* __restrict__ vc, const float* __restrict__ agg_rep,
                       const float* __restrict__ Wpred, float* __restrict__ out){
  __shared__ __align__(16) float sBl[EE];
  __shared__ __align__(16) float vcl[EE];
  __shared__ float p[SS]; __shared__ float red[SS]; __shared__ float rr[D2];
  int b=blockIdx.x, tid=threadIdx.x;
  if (tid<EE){ sBl[tid]=sB[(size_t)b*EE+tid]; vcl[tid]=vc[tid]; }
  __syncthreads();
  const float* rowA = sA + ((size_t)b*SS+tid)*EE;
  float sc=0.f;
  #pragma unroll
  for (int e=0;e<EE;e+=4){
    float4 a=*(const float4*)(rowA+e);
    float4 bb=*(const float4*)(sBl+e);
    float4 vw=*(const float4*)(vcl+e);
    sc += vw.x*(a.x+bb.x)+vw.y*(a.y+bb.y)+vw.z*(a.z+bb.z)+vw.w*(a.w+bb.w);   // note: no tanh
  }
  softmax256(sc, red, p);
  float o=0.f;
  for (int s=0;s<SS;s++) o += p[s]*agg_rep[((size_t)b*SS+s)*D2+tid];
  rr[tid]=o; __syncthreads();
  if (tid<LL){
    float a=0.f;
    const float* wr = Wpred + (size_t)tid*D2;
    for (int d=0;d<D2;d++) a += wr[d]*rr[d];
    out[(size_t)b*LL+tid]=sigmoidf_(a);
  }
}

extern "C" void kernel_launch(void* const* d_in, const int* in_sizes, int n_in,
                              void* d_out, int out_size, void* d_ws, size_t ws_size,
                              hipStream_t stream){
  (void)in_sizes; (void)n_in; (void)out_size; (void)ws_size;
  const int*   inp = (const int*)d_in[0];
  const float* emb = (const float*)d_in[1];
  const float* enc_wih_f=(const float*)d_in[2],  *enc_whh_f=(const float*)d_in[3],
             *enc_bih_f=(const float*)d_in[4],  *enc_bhh_f=(const float*)d_in[5];
  const float* enc_wih_b=(const float*)d_in[6],  *enc_whh_b=(const float*)d_in[7],
             *enc_bih_b=(const float*)d_in[8],  *enc_bhh_b=(const float*)d_in[9];
  const float* hid_wih_f=(const float*)d_in[10], *hid_whh_f=(const float*)d_in[11],
             *hid_bih_f=(const float*)d_in[12], *hid_bhh_f=(const float*)d_in[13];
  const float* hid_wih_b=(const float*)d_in[14], *hid_whh_b=(const float*)d_in[15],
             *hid_bih_b=(const float*)d_in[16], *hid_bhh_b=(const float*)d_in[17];
  const float* agg_wih_f=(const float*)d_in[18], *agg_whh_f=(const float*)d_in[19],
             *agg_bih_f=(const float*)d_in[20], *agg_bhh_f=(const float*)d_in[21];
  const float* agg_wih_b=(const float*)d_in[22], *agg_whh_b=(const float*)d_in[23],
             *agg_bih_b=(const float*)d_in[24], *agg_bhh_b=(const float*)d_in[25];
  const float* Wc1=(const float*)d_in[26], *Wc2=(const float*)d_in[27], *vc=(const float*)d_in[28];
  const float* Wb =(const float*)d_in[29];
  const float* Wd =(const float*)d_in[30], *vd=(const float*)d_in[31];
  const float* Wm =(const float*)d_in[32], *vm=(const float*)d_in[33];
  const float* Ws =(const float*)d_in[34], *vs=(const float*)d_in[35];
  const float* Wp =(const float*)d_in[36], *vp=(const float*)d_in[37];
  const float* Wpred=(const float*)d_in[38];

  float* ws = (float*)d_ws;
  size_t o = 0;
  float* x       = ws + o; o += (size_t)BB*SS*DD;     // 307200
  float* gxf     = ws + o; o += (size_t)BB*SS*H3;     // 393216
  float* gxb     = ws + o; o += (size_t)BB*SS*H3;
  float* hp      = ws + o; o += (size_t)BB*SS*D2;
  float* hq      = ws + o; o += (size_t)BB*SS*D2;
  float* hidden  = ws + o; o += (size_t)2*BB*EE;
  float* s1      = ws + o; o += (size_t)BB*SS*EE;
  float* s2      = ws + o; o += (size_t)BB*SS*EE;
  float* Am      = ws + o; o += (size_t)BB*SS*EE;
  float* Bm      = ws + o; o += (size_t)BB*SS*EE;
  float* Pb      = ws + o; o += (size_t)BB*SS*D2;
  float* spj     = ws + o; o += (size_t)BB*SS*EE;
  float* scd     = ws + o; o += (size_t)BB*SS*SS;
  float* scs     = ws + o; o += (size_t)BB*SS*SS;
  float* agg     = ws + o; o += (size_t)BB*SS*D12;
  float* agg_rep = ws + o; o += (size_t)BB*SS*D2;
  float* rl      = ws + o; o += (size_t)BB*D2;
  float* sA      = ws + o; o += (size_t)BB*SS*EE;
  float* sB      = ws + o; o += (size_t)BB*EE;

  auto mm=[&](const float* X,const float* W,const float* bias,float* outp,int M,int N,int K){
    dim3 g((N+63)/64,(M+63)/64);
    k_matmul<<<g,256,0,stream>>>(X,W,bias,outp,M,N,K);
  };

  k_embed<<<BB*SS,256,0,stream>>>(inp, emb, x);

  // encoder BiGRU
  mm(x, enc_wih_f, enc_bih_f, gxf, BB*SS, H3, DD);
  mm(x, enc_wih_b, enc_bih_b, gxb, BB*SS, H3, DD);
  k_gru_scan<<<dim3(BB,2),384,0,stream>>>(gxf,gxb,enc_whh_f,enc_whh_b,enc_bhh_f,enc_bhh_b,
                                          nullptr,hp,hidden);
  // hidden BiGRU
  mm(hp, hid_wih_f, hid_bih_f, gxf, BB*SS, H3, D2);
  mm(hp, hid_wih_b, hid_bih_b, gxb, BB*SS, H3, D2);
  k_gru_scan<<<dim3(BB,2),384,0,stream>>>(gxf,gxb,hid_whh_f,hid_whh_b,hid_bhh_f,hid_bhh_b,
                                          hidden,hq,nullptr);
  // projections
  mm(hp, Wc1, nullptr, s1,  BB*SS, EE, D2);
  mm(hq, Wc2, nullptr, s2,  BB*SS, EE, D2);
  mm(hp, Wm,  nullptr, Am,  BB*SS, EE, D2);
  mm(hq, Wm,  nullptr, Bm,  BB*SS, EE, D2);
  mm(hp, Wb,  nullptr, Pb,  BB*SS, D2, D2);
  mm(hq, Wp,  nullptr, spj, BB*SS, EE, D2);

  // agg slices: hq(0) pts(256) ptc(512) ptd(768) ptb(1024) ptm(1280)
  k_copy_hq<<<BB*SS,256,0,stream>>>(hq, agg);
  dim3 gq(SS,BB);
  k_attn_add<<<gq,256,0,stream>>>(s1,s2,vc, 1.f, hp, agg, 512);   // ptc
  k_attn_add<<<gq,256,0,stream>>>(Am,Bm,vm,-1.f, hp, agg, 1280);  // ptm (separable)
  k_attn_bil<<<gq,256,0,stream>>>(Pb,hq,hp,agg,1024);             // ptb
  k_mulattn_score<<<dim3(4,SS,BB),256,0,stream>>>(hp,hq,Wd,vd,scd);
  k_softmax_pv<<<gq,256,0,stream>>>(scd,hp,agg,768);              // ptd
  k_mulattn_score<<<dim3(4,SS,BB),256,0,stream>>>(hq,hq,Ws,vs,scs);
  k_softmax_pv<<<gq,256,0,stream>>>(scs,hq,agg,256);              // pts

  // aggregation BiGRU
  mm(agg, agg_wih_f, agg_bih_f, gxf, BB*SS, H3, D12);
  mm(agg, agg_wih_b, agg_bih_b, gxb, BB*SS, H3, D12);
  k_gru_scan<<<dim3(BB,2),384,0,stream>>>(gxf,gxb,agg_whh_f,agg_whh_b,agg_bhh_f,agg_bhh_b,
                                          nullptr,agg_rep,nullptr);

  // pooling + prediction
  k_rl<<<BB,256,0,stream>>>(spj,hq,vp,rl);
  mm(agg_rep, Wc1, nullptr, sA, BB*SS, EE, D2);
  mm(rl,      Wc2, nullptr, sB, BB,    EE, D2);
  k_final<<<BB,256,0,stream>>>(sA,sB,vc,agg_rep,Wpred,(float*)d_out);
}

// Round 2
// 2391.185 us; speedup vs baseline: 1.0868x; 1.0868x over previous
//
#include <hip/hip_runtime.h>
#include <math.h>

#define BB 4
#define SS 256
#define DD 300
#define EE 128
#define LL 20
#define H3 384
#define D2 256   // 2E
#define D12 1536 // 12E

__device__ __forceinline__ float sigmoidf_(float x){ return 1.f/(1.f+expf(-x)); }

// ---------------- embedding gather ----------------
__global__ void k_embed(const int* __restrict__ inp, const float* __restrict__ emb,
                        float* __restrict__ x){
  int row = blockIdx.x;            // b*S+s
  int idx = inp[row];
  const float* src = emb + (size_t)idx*DD;
  float* dst = x + (size_t)row*DD;
  for (int d=threadIdx.x; d<DD; d+=blockDim.x) dst[d]=src[d];
}

// ---------------- generic matmul: out[M,N] = X[M,K] @ W[N,K]^T + bias ----------------
__global__ __launch_bounds__(256) void k_matmul(const float* __restrict__ X, const float* __restrict__ W,
                        const float* __restrict__ bias, float* __restrict__ out,
                        int M, int N, int K){
  __shared__ __align__(16) float Xs[16][68];   // [kk][m]
  __shared__ __align__(16) float Ws[16][68];   // [kk][n]
  int tid=threadIdx.x, tx=tid&15, ty=tid>>4;
  int m0=blockIdx.y*64, n0=blockIdx.x*64;
  float acc[4][4]={};
  for (int k0=0;k0<K;k0+=16){
    #pragma unroll
    for (int i=0;i<4;i++){
      int idx=tid+i*256; int r=idx>>4, kk=idx&15; int gk=k0+kk;
      int gm=m0+r; Xs[kk][r] = (gm<M && gk<K)? X[(size_t)gm*K+gk] : 0.f;
      int gn=n0+r; Ws[kk][r] = (gn<N && gk<K)? W[(size_t)gn*K+gk] : 0.f;
    }
    __syncthreads();
    #pragma unroll
    for (int kk=0;kk<16;kk++){
      float4 a=*(const float4*)&Xs[kk][ty*4];
      float4 b=*(const float4*)&Ws[kk][tx*4];
      float av[4]={a.x,a.y,a.z,a.w};
      float bv[4]={b.x,b.y,b.z,b.w};
      #pragma unroll
      for (int i=0;i<4;i++)
        #pragma unroll
        for (int j=0;j<4;j++) acc[i][j] += av[i]*bv[j];
    }
    __syncthreads();
  }
  #pragma unroll
  for (int i=0;i<4;i++){
    int gm=m0+ty*4+i; if (gm>=M) continue;
    #pragma unroll
    for (int j=0;j<4;j++){
      int gn=n0+tx*4+j; if (gn>=N) continue;
      out[(size_t)gm*N+gn] = acc[i][j] + (bias? bias[gn]:0.f);
    }
  }
}

// ---------------- GRU scan (one block per (batch, direction)) ----------------
// 512 threads: tid = r*4 + part. Thread group r handles gate rows r, r+128, r+256;
// part = quarter of the k dimension (32 floats). Weights live in 24 float4 VGPRs
// (static indices — the R1 version's wrow[128] spilled: 2.34 GB FETCH_SIZE/scan).
// Gate partials combined via shfl_xor within the 4-lane group → no gh LDS trip,
// one barrier per step (double-buffered h).
__global__ __launch_bounds__(512, 2) void k_gru_scan(const float* __restrict__ gxf, const float* __restrict__ gxb,
                          const float* __restrict__ whhf, const float* __restrict__ whhb,
                          const float* __restrict__ bhhf, const float* __restrict__ bhhb,
                          const float* __restrict__ h0,   // [2,B,E] or null
                          float* __restrict__ out,        // [B,S,2E]
                          float* __restrict__ hT){        // [2,B,E] or null
  int b=blockIdx.x, dir=blockIdx.y, tid=threadIdx.x;
  const float* gx  = dir? gxb : gxf;
  const float* whh = dir? whhb : whhf;
  const float* bhh = dir? bhhb : bhhf;
  int r = tid>>2, part = tid&3, phase = r&7;
  // staggered chunk order: chunk j of this thread is slice jj=(j+phase)&7 of its quarter
  float4 w_r[8], w_z[8], w_n[8];
  #pragma unroll
  for (int j=0;j<8;j++){
    int jj=(j+phase)&7;
    int off = part*32 + jj*4;
    w_r[j] = *(const float4*)&whh[(size_t)r*EE        + off];
    w_z[j] = *(const float4*)&whh[(size_t)(r+128)*EE  + off];
    w_n[j] = *(const float4*)&whh[(size_t)(r+256)*EE  + off];
  }
  float b_r=bhh[r], b_z=bhh[r+128], b_n=bhh[r+256];
  __shared__ __align__(16) float h[2][EE];
  float hprev = h0? h0[((size_t)dir*BB+b)*EE + r] : 0.f;
  if (part==0) h[0][r] = hprev;
  // prefetch gx for first step
  float xr=0.f,xz=0.f,xn=0.f;
  {
    int s0 = dir? (SS-1) : 0;
    const float* g0 = gx + ((size_t)b*SS+s0)*H3;
    if (part==0){ xr=g0[r]; xz=g0[EE+r]; xn=g0[2*EE+r]; }
  }
  __syncthreads();
  int cur=0;
  for (int t=0;t<SS;t++){
    int s = dir? (SS-1-t) : t;
    float ar=0.f, az=0.f, an=0.f;
    #pragma unroll
    for (int j=0;j<8;j++){
      int jj=(j+phase)&7;
      float4 hv = *(const float4*)&h[cur][part*32 + jj*4];
      ar += w_r[j].x*hv.x + w_r[j].y*hv.y + w_r[j].z*hv.z + w_r[j].w*hv.w;
      az += w_z[j].x*hv.x + w_z[j].y*hv.y + w_z[j].z*hv.z + w_z[j].w*hv.w;
      an += w_n[j].x*hv.x + w_n[j].y*hv.y + w_n[j].z*hv.z + w_n[j].w*hv.w;
    }
    ar += __shfl_xor(ar,1); ar += __shfl_xor(ar,2);
    az += __shfl_xor(az,1); az += __shfl_xor(az,2);
    an += __shfl_xor(an,1); an += __shfl_xor(an,2);
    if (part==0){
      float rg = sigmoidf_(xr + ar + b_r);
      float zg = sigmoidf_(xz + az + b_z);
      float ng = tanhf(xn + rg*(an + b_n));
      float h2 = (1.f-zg)*ng + zg*hprev;
      hprev = h2;
      h[cur^1][r] = h2;
      out[((size_t)b*SS+s)*D2 + dir*EE + r] = h2;
      if (t+1<SS){
        int sn = dir? (SS-2-t) : (t+1);
        const float* gn = gx + ((size_t)b*SS+sn)*H3;
        xr=gn[r]; xz=gn[EE+r]; xn=gn[2*EE+r];
      }
    }
    cur^=1;
    __syncthreads();
  }
  if (hT && part==0) hT[((size_t)dir*BB+b)*EE+r]=hprev;
}

__global__ void k_copy_hq(const float* __restrict__ hq, float* __restrict__ agg){
  int row=blockIdx.x;
  agg[(size_t)row*D12 + threadIdx.x] = hq[(size_t)row*D2 + threadIdx.x];
}

// --------- block softmax over 256 values, p[tid] gets probability ---------
__device__ __forceinline__ void softmax256(float val, float* red, float* p){
  int tid=threadIdx.x;
  red[tid]=val; __syncthreads();
  for (int st=128; st>0; st>>=1){ if (tid<st) red[tid]=fmaxf(red[tid],red[tid+st]); __syncthreads(); }
  float mx=red[0]; __syncthreads();
  float ex=expf(val-mx); red[tid]=ex; __syncthreads();
  for (int st=128; st>0; st>>=1){ if (tid<st) red[tid]+=red[tid+st]; __syncthreads(); }
  float inv=1.f/red[0];
  p[tid]=ex*inv; __syncthreads();
}

// ---------------- additive-style attention (ptc: sign=+1, ptm: sign=-1) ----------------
__global__ __launch_bounds__(256) void k_attn_add(const float* __restrict__ A, const float* __restrict__ Bq,
                          const float* __restrict__ v, float sign,
                          const float* __restrict__ V, float* __restrict__ aggout, int off){
  __shared__ __align__(16) float bq[EE];
  __shared__ __align__(16) float vv[EE];
  __shared__ float p[SS]; __shared__ float red[SS];
  int q=blockIdx.x, b=blockIdx.y, tid=threadIdx.x;
  if (tid<EE){ bq[tid]=sign*Bq[((size_t)b*SS+q)*EE+tid]; vv[tid]=v[tid]; }
  __syncthreads();
  const float* Ar = A + ((size_t)b*SS+tid)*EE;   // thread = key index k
  float s=0.f;
  #pragma unroll
  for (int e=0;e<EE;e+=4){
    float4 a=*(const float4*)(Ar+e);
    float4 bb=*(const float4*)(bq+e);
    float4 vw=*(const float4*)(vv+e);
    s += vw.x*tanhf(a.x+bb.x)+vw.y*tanhf(a.y+bb.y)+vw.z*tanhf(a.z+bb.z)+vw.w*tanhf(a.w+bb.w);
  }
  softmax256(s, red, p);
  const float* V0 = V + (size_t)b*SS*D2;
  float o=0.f;
  for (int k=0;k<SS;k++) o += p[k]*V0[(size_t)k*D2+tid];
  aggout[((size_t)b*SS+q)*D12 + off + tid] = o;
}

// ---------------- bilinear attention (ptb) ----------------
__global__ __launch_bounds__(256) void k_attn_bil(const float* __restrict__ Pb, const float* __restrict__ hq,
                          const float* __restrict__ V, float* __restrict__ aggout, int off){
  __shared__ __align__(16) float hqq[D2];
  __shared__ float p[SS]; __shared__ float red[SS];
  int q=blockIdx.x, b=blockIdx.y, tid=threadIdx.x;
  hqq[tid]=hq[((size_t)b*SS+q)*D2+tid];
  __syncthreads();
  const float* Pr = Pb + ((size_t)b*SS+tid)*D2;
  float s=0.f;
  #pragma unroll
  for (int d=0;d<D2;d+=4){
    float4 a=*(const float4*)(Pr+d);
    float4 hh=*(const float4*)(hqq+d);
    s += a.x*hh.x+a.y*hh.y+a.z*hh.z+a.w*hh.w;
  }
  softmax256(s, red, p);
  const float* V0 = V + (size_t)b*SS*D2;
  float o=0.f;
  for (int k=0;k<SS;k++) o += p[k]*V0[(size_t)k*D2+tid];
  aggout[((size_t)b*SS+q)*D12 + off + tid] = o;
}

// ------- ptd/pts score: sc[b,q,k] = sum_e v[e] tanh( sum_d W[e,d] keys[b,k,d] qm[b,q,d] ) -------
// grid (4 m-tiles, S, B); 256 threads; per block 64 k x 128 e, 4x8 per thread.
__global__ __launch_bounds__(256) void k_mulattn_score(const float* __restrict__ keys, const float* __restrict__ qm,
                               const float* __restrict__ W, const float* __restrict__ v,
                               float* __restrict__ scbuf){
  __shared__ __align__(16) float XsT[16][68];    // [kk][m]  keyq chunk
  __shared__ __align__(16) float WsT[16][132];   // [kk][n]  W chunk
  __shared__ float hqq[D2];
  int m0=blockIdx.x*64, q=blockIdx.y, b=blockIdx.z;
  int tid=threadIdx.x, tx=tid&15, ty=tid>>4;
  hqq[tid]=qm[((size_t)b*SS+q)*D2+tid];
  __syncthreads();
  const float* kb = keys + (size_t)b*SS*D2;
  float acc[4][8]={};
  for (int d0=0; d0<D2; d0+=16){
    #pragma unroll
    for (int i=0;i<4;i++){
      int idx=tid+i*256; int m=idx>>4, kk=idx&15;
      XsT[kk][m]=kb[(size_t)(m0+m)*D2 + d0+kk]*hqq[d0+kk];
    }
    #pragma unroll
    for (int i=0;i<8;i++){
      int idx=tid+i*256; int n=idx>>4, kk=idx&15;
      WsT[kk][n]=W[(size_t)n*D2 + d0+kk];
    }
    __syncthreads();
    #pragma unroll
    for (int kk=0;kk<16;kk++){
      float4 a =*(const float4*)&XsT[kk][ty*4];
      float4 b0=*(const float4*)&WsT[kk][tx*8];
      float4 b1=*(const float4*)&WsT[kk][tx*8+4];
      float av[4]={a.x,a.y,a.z,a.w};
      float bv[8]={b0.x,b0.y,b0.z,b0.w,b1.x,b1.y,b1.z,b1.w};
      #pragma unroll
      for (int i=0;i<4;i++)
        #pragma unroll
        for (int j=0;j<8;j++) acc[i][j] += av[i]*bv[j];
    }
    __syncthreads();
  }
  float vreg[8];
  #pragma unroll
  for (int j=0;j<8;j++) vreg[j]=v[tx*8+j];
  #pragma unroll
  for (int i=0;i<4;i++){
    float s=0.f;
    #pragma unroll
    for (int j=0;j<8;j++) s += vreg[j]*tanhf(acc[i][j]);
    s += __shfl_xor(s,1,16);
    s += __shfl_xor(s,2,16);
    s += __shfl_xor(s,4,16);
    s += __shfl_xor(s,8,16);
    if (tx==0) scbuf[((size_t)b*SS+q)*SS + m0 + ty*4 + i] = s;
  }
}

// ---------------- softmax over precomputed scores + weighted value sum ----------------
__global__ __launch_bounds__(256) void k_softmax_pv(const float* __restrict__ scbuf, const float* __restrict__ V,
                            float* __restrict__ aggout, int off){
  __shared__ float p[SS]; __shared__ float red[SS];
  int q=blockIdx.x, b=blockIdx.y, tid=threadIdx.x;
  float val = scbuf[((size_t)b*SS+q)*SS + tid];
  softmax256(val, red, p);
  const float* V0 = V + (size_t)b*SS*D2;
  float o=0.f;
  for (int k=0;k<SS;k++) o += p[k]*V0[(size_t)k*D2+tid];
  aggout[((size_t)b*SS+q)*D12 + off + tid] = o;
}

// ---------------- rl pooling over hq ----------------
__global__ __launch_bounds__(256) void k_rl(const float* __restrict__ spj, const float* __restrict__ hq,
                    const float* __restrict__ vp, float* __restrict__ rl){
  __shared__ __align__(16) float vpl[EE];
  __shared__ float p[SS]; __shared__ float red[SS];
  int b=blockIdx.x, tid=threadIdx.x;
  if (tid<EE) vpl[tid]=vp[tid];
  __syncthreads();
  const float* row = spj + ((size_t)b*SS+tid)*EE;
  float sj=0.f;
  #pragma unroll
  for (int e=0;e<EE;e+=4){
    float4 a=*(const float4*)(row+e);
    float4 vw=*(const float4*)(vpl+e);
    sj += vw.x*tanhf(a.x)+vw.y*tanhf(a.y)+vw.z*tanhf(a.z)+vw.w*tanhf(a.w);
  }
  softmax256(sj, red, p);
  float o=0.f;
  for (int s=0;s<SS;s++) o += p[s]*hq[((size_t)b*SS+s)*D2+tid];
  rl[(size_t)b*D2+tid]=o;
}

// ---------------- final pooling + prediction ----------------
__global__ __launch_bounds__(256) void k_final(const float* __restrict__ sA, const float* __restrict__ sB,
                       const float* __restrict__ vc, const float* __restrict__ agg_rep,
                       const float* __restrict__ Wpred, float* __restrict__ out){
  __shared__ __align__(16) float sBl[EE];
  __shared__ __align__(16) float vcl[EE];
  __shared__ float p[SS]; __shared__ float red[SS]; __shared__ float rr[D2];
  int b=blockIdx.x, tid=threadIdx.x;
  if (tid<EE){ sBl[tid]=sB[(size_t)b*EE+tid]; vcl[tid]=vc[tid]; }
  __syncthreads();
  const float* rowA = sA + ((size_t)b*SS+tid)*EE;
  float sc=0.f;
  #pragma unroll
  for (int e=0;e<EE;e+=4){
    float4 a=*(const float4*)(rowA+e);
    float4 bb=*(const float4*)(sBl+e);
    float4 vw=*(const float4*)(vcl+e);
    sc += vw.x*(a.x+bb.x)+vw.y*(a.y+bb.y)+vw.z*(a.z+bb.z)+vw.w*(a.w+bb.w);   // note: no tanh
  }
  softmax256(sc, red, p);
  float o=0.f;
  for (int s=0;s<SS;s++) o += p[s]*agg_rep[((size_t)b*SS+s)*D2+tid];
  rr[tid]=o; __syncthreads();
  if (tid<LL){
    float a=0.f;
    const float* wr = Wpred + (size_t)tid*D2;
    for (int d=0;d<D2;d++) a += wr[d]*rr[d];
    out[(size_t)b*LL+tid]=sigmoidf_(a);
  }
}

extern "C" void kernel_launch(void* const* d_in, const int* in_sizes, int n_in,
                              void* d_out, int out_size, void* d_ws, size_t ws_size,
                              hipStream_t stream){
  (void)in_sizes; (void)n_in; (void)out_size; (void)ws_size;
  const int*   inp = (const int*)d_in[0];
  const float* emb = (const float*)d_in[1];
  const float* enc_wih_f=(const float*)d_in[2],  *enc_whh_f=(const float*)d_in[3],
             *enc_bih_f=(const float*)d_in[4],  *enc_bhh_f=(const float*)d_in[5];
  const float* enc_wih_b=(const float*)d_in[6],  *enc_whh_b=(const float*)d_in[7],
             *enc_bih_b=(const float*)d_in[8],  *enc_bhh_b=(const float*)d_in[9];
  const float* hid_wih_f=(const float*)d_in[10], *hid_whh_f=(const float*)d_in[11],
             *hid_bih_f=(const float*)d_in[12], *hid_bhh_f=(const float*)d_in[13];
  const float* hid_wih_b=(const float*)d_in[14], *hid_whh_b=(const float*)d_in[15],
             *hid_bih_b=(const float*)d_in[16], *hid_bhh_b=(const float*)d_in[17];
  const float* agg_wih_f=(const float*)d_in[18], *agg_whh_f=(const float*)d_in[19],
             *agg_bih_f=(const float*)d_in[20], *agg_bhh_f=(const float*)d_in[21];
  const float* agg_wih_b=(const float*)d_in[22], *agg_whh_b=(const float*)d_in[23],
             *agg_bih_b=(const float*)d_in[24], *agg_bhh_b=(const float*)d_in[25];
  const float* Wc1=(const float*)d_in[26], *Wc2=(const float*)d_in[27], *vc=(const float*)d_in[28];
  const float* Wb =(const float*)d_in[29];
  const float* Wd =(const float*)d_in[30], *vd=(const float*)d_in[31];
  const float* Wm =(const float*)d_in[32], *vm=(const float*)d_in[33];
  const float* Ws =(const float*)d_in[34], *vs=(const float*)d_in[35];
  const float* Wp =(const float*)d_in[36], *vp=(const float*)d_in[37];
  const float* Wpred=(const float*)d_in[38];

  float* ws = (float*)d_ws;
  size_t o = 0;
  float* x       = ws + o; o += (size_t)BB*SS*DD;     // 307200
  float* gxf     = ws + o; o += (size_t)BB*SS*H3;     // 393216
  float* gxb     = ws + o; o += (size_t)BB*SS*H3;
  float* hp      = ws + o; o += (size_t)BB*SS*D2;
  float* hq      = ws + o; o += (size_t)BB*SS*D2;
  float* hidden  = ws + o; o += (size_t)2*BB*EE;
  float* s1      = ws + o; o += (size_t)BB*SS*EE;
  float* s2      = ws + o; o += (size_t)BB*SS*EE;
  float* Am      = ws + o; o += (size_t)BB*SS*EE;
  float* Bm      = ws + o; o += (size_t)BB*SS*EE;
  float* Pb      = ws + o; o += (size_t)BB*SS*D2;
  float* spj     = ws + o; o += (size_t)BB*SS*EE;
  float* scd     = ws + o; o += (size_t)BB*SS*SS;
  float* scs     = ws + o; o += (size_t)BB*SS*SS;
  float* agg     = ws + o; o += (size_t)BB*SS*D12;
  float* agg_rep = ws + o; o += (size_t)BB*SS*D2;
  float* rl      = ws + o; o += (size_t)BB*D2;
  float* sA      = ws + o; o += (size_t)BB*SS*EE;
  float* sB      = ws + o; o += (size_t)BB*EE;

  auto mm=[&](const float* X,const float* W,const float* bias,float* outp,int M,int N,int K){
    dim3 g((N+63)/64,(M+63)/64);
    k_matmul<<<g,256,0,stream>>>(X,W,bias,outp,M,N,K);
  };

  k_embed<<<BB*SS,256,0,stream>>>(inp, emb, x);

  // encoder BiGRU
  mm(x, enc_wih_f, enc_bih_f, gxf, BB*SS, H3, DD);
  mm(x, enc_wih_b, enc_bih_b, gxb, BB*SS, H3, DD);
  k_gru_scan<<<dim3(BB,2),512,0,stream>>>(gxf,gxb,enc_whh_f,enc_whh_b,enc_bhh_f,enc_bhh_b,
                                          nullptr,hp,hidden);
  // hidden BiGRU
  mm(hp, hid_wih_f, hid_bih_f, gxf, BB*SS, H3, D2);
  mm(hp, hid_wih_b, hid_bih_b, gxb, BB*SS, H3, D2);
  k_gru_scan<<<dim3(BB,2),512,0,stream>>>(gxf,gxb,hid_whh_f,hid_whh_b,hid_bhh_f,hid_bhh_b,
                                          hidden,hq,nullptr);
  // projections
  mm(hp, Wc1, nullptr, s1,  BB*SS, EE, D2);
  mm(hq, Wc2, nullptr, s2,  BB*SS, EE, D2);
  mm(hp, Wm,  nullptr, Am,  BB*SS, EE, D2);
  mm(hq, Wm,  nullptr, Bm,  BB*SS, EE, D2);
  mm(hp, Wb,  nullptr, Pb,  BB*SS, D2, D2);
  mm(hq, Wp,  nullptr, spj, BB*SS, EE, D2);

  // agg slices: hq(0) pts(256) ptc(512) ptd(768) ptb(1024) ptm(1280)
  k_copy_hq<<<BB*SS,256,0,stream>>>(hq, agg);
  dim3 gq(SS,BB);
  k_attn_add<<<gq,256,0,stream>>>(s1,s2,vc, 1.f, hp, agg, 512);   // ptc
  k_attn_add<<<gq,256,0,stream>>>(Am,Bm,vm,-1.f, hp, agg, 1280);  // ptm (separable)
  k_attn_bil<<<gq,256,0,stream>>>(Pb,hq,hp,agg,1024);             // ptb
  k_mulattn_score<<<dim3(4,SS,BB),256,0,stream>>>(hp,hq,Wd,vd,scd);
  k_softmax_pv<<<gq,256,0,stream>>>(scd,hp,agg,768);              // ptd
  k_mulattn_score<<<dim3(4,SS,BB),256,0,stream>>>(hq,hq,Ws,vs,scs);
  k_softmax_pv<<<gq,256,0,stream>>>(scs,hq,agg,256);              // pts

  // aggregation BiGRU
  mm(agg, agg_wih_f, agg_bih_f, gxf, BB*SS, H3, D12);
  mm(agg, agg_wih_b, agg_bih_b, gxb, BB*SS, H3, D12);
  k_gru_scan<<<dim3(BB,2),512,0,stream>>>(gxf,gxb,agg_whh_f,agg_whh_b,agg_bhh_f,agg_bhh_b,
                                          nullptr,agg_rep,nullptr);

  // pooling + prediction
  k_rl<<<BB,256,0,stream>>>(spj,hq,vp,rl);
  mm(agg_rep, Wc1, nullptr, sA, BB*SS, EE, D2);
  mm(rl,      Wc2, nullptr, sB, BB,    EE, D2);
  k_final<<<BB,256,0,stream>>>(sA,sB,vc,agg_rep,Wpred,(float*)d_out);
}

// Round 4
// 1855.725 us; speedup vs baseline: 1.4003x; 1.2885x over previous
//
#include <hip/hip_runtime.h>
#include <math.h>

#define BB 4
#define SS 256
#define DD 300
#define EE 128
#define LL 20
#define H3 384
#define D2 256   // 2E
#define D12 1536 // 12E

typedef __attribute__((ext_vector_type(8)))  short short8;
typedef __attribute__((ext_vector_type(16))) float f32x16;

__device__ __forceinline__ float tanh_fast(float x){
  // tanh(x) = 1 - 2/(exp(2x)+1); exact at +-inf, ~1e-6 rel err. ~5 VALU vs ocml's ~30.
  float e = __expf(2.f*x);
  return 1.f - 2.f/(e+1.f);
}
__device__ __forceinline__ float sigmoidf_(float x){ return 1.f/(1.f+__expf(-x)); }
__device__ __forceinline__ float bf16_to_f(unsigned u){ return __builtin_bit_cast(float, u<<16); }
__device__ __forceinline__ float bf16hi_to_f(unsigned u){ return __builtin_bit_cast(float, u & 0xFFFF0000u); }
__device__ __forceinline__ unsigned bf16_rne(float f){
  unsigned u = __builtin_bit_cast(unsigned, f);
  return (u + 0x7FFFu + ((u>>16)&1u)) >> 16;
}
__device__ __forceinline__ unsigned pack_bf16x2(float lo, float hi){
  return bf16_rne(lo) | (bf16_rne(hi)<<16);
}

// ---------------- f32 -> bf16 (RNE) conversion, 2 elems/thread ----------------
__global__ void k_cvt_bf16(const float* __restrict__ src, unsigned short* __restrict__ dst, int n2){
  int i = blockIdx.x*blockDim.x + threadIdx.x;   // pair index
  if (i < n2){
    float2 f = *(const float2*)(src + 2*i);
    *(unsigned*)(dst + 2*i) = pack_bf16x2(f.x, f.y);
  }
}

// ---------------- embedding gather ----------------
__global__ void k_embed(const int* __restrict__ inp, const float* __restrict__ emb,
                        float* __restrict__ x){
  int row = blockIdx.x;            // b*S+s
  int idx = inp[row];
  const float* src = emb + (size_t)idx*DD;
  float* dst = x + (size_t)row*DD;
  for (int d=threadIdx.x; d<DD; d+=blockDim.x) dst[d]=src[d];
}

// ---------------- generic matmul: out[M,N] = X[M,K] @ W[N,K]^T + bias ----------------
__global__ __launch_bounds__(256) void k_matmul(const float* __restrict__ X, const float* __restrict__ W,
                        const float* __restrict__ bias, float* __restrict__ out,
                        int M, int N, int K){
  __shared__ __align__(16) float Xs[16][68];   // [kk][m]
  __shared__ __align__(16) float Ws[16][68];   // [kk][n]
  int tid=threadIdx.x, tx=tid&15, ty=tid>>4;
  int m0=blockIdx.y*64, n0=blockIdx.x*64;
  float acc[4][4]={};
  for (int k0=0;k0<K;k0+=16){
    #pragma unroll
    for (int i=0;i<4;i++){
      int idx=tid+i*256; int r=idx>>4, kk=idx&15; int gk=k0+kk;
      int gm=m0+r; Xs[kk][r] = (gm<M && gk<K)? X[(size_t)gm*K+gk] : 0.f;
      int gn=n0+r; Ws[kk][r] = (gn<N && gk<K)? W[(size_t)gn*K+gk] : 0.f;
    }
    __syncthreads();
    #pragma unroll
    for (int kk=0;kk<16;kk++){
      float4 a=*(const float4*)&Xs[kk][ty*4];
      float4 b=*(const float4*)&Ws[kk][tx*4];
      float av[4]={a.x,a.y,a.z,a.w};
      float bv[4]={b.x,b.y,b.z,b.w};
      #pragma unroll
      for (int i=0;i<4;i++)
        #pragma unroll
        for (int j=0;j<4;j++) acc[i][j] += av[i]*bv[j];
    }
    __syncthreads();
  }
  #pragma unroll
  for (int i=0;i<4;i++){
    int gm=m0+ty*4+i; if (gm>=M) continue;
    #pragma unroll
    for (int j=0;j<4;j++){
      int gn=n0+tx*4+j; if (gn>=N) continue;
      out[(size_t)gm*N+gn] = acc[i][j] + (bias? bias[gn]:0.f);
    }
  }
}

// ---------------- GRU scan (one block per (batch, direction)) ----------------
__global__ __launch_bounds__(512, 2) void k_gru_scan(const float* __restrict__ gxf, const float* __restrict__ gxb,
                          const float* __restrict__ whhf, const float* __restrict__ whhb,
                          const float* __restrict__ bhhf, const float* __restrict__ bhhb,
                          const float* __restrict__ h0,   // [2,B,E] or null
                          float* __restrict__ out,        // [B,S,2E]
                          float* __restrict__ hT){        // [2,B,E] or null
  int b=blockIdx.x, dir=blockIdx.y, tid=threadIdx.x;
  const float* gx  = dir? gxb : gxf;
  const float* whh = dir? whhb : whhf;
  const float* bhh = dir? bhhb : bhhf;
  int r = tid>>2, part = tid&3, phase = r&7;
  float4 w_r[8], w_z[8], w_n[8];
  #pragma unroll
  for (int j=0;j<8;j++){
    int jj=(j+phase)&7;
    int off = part*32 + jj*4;
    w_r[j] = *(const float4*)&whh[(size_t)r*EE        + off];
    w_z[j] = *(const float4*)&whh[(size_t)(r+128)*EE  + off];
    w_n[j] = *(const float4*)&whh[(size_t)(r+256)*EE  + off];
  }
  float b_r=bhh[r], b_z=bhh[r+128], b_n=bhh[r+256];
  __shared__ __align__(16) float h[2][EE];
  float hprev = h0? h0[((size_t)dir*BB+b)*EE + r] : 0.f;
  if (part==0) h[0][r] = hprev;
  float xr=0.f,xz=0.f,xn=0.f;
  {
    int s0 = dir? (SS-1) : 0;
    const float* g0 = gx + ((size_t)b*SS+s0)*H3;
    if (part==0){ xr=g0[r]; xz=g0[EE+r]; xn=g0[2*EE+r]; }
  }
  __syncthreads();
  int cur=0;
  for (int t=0;t<SS;t++){
    int s = dir? (SS-1-t) : t;
    float ar=0.f, az=0.f, an=0.f;
    #pragma unroll
    for (int j=0;j<8;j++){
      int jj=(j+phase)&7;
      float4 hv = *(const float4*)&h[cur][part*32 + jj*4];
      ar += w_r[j].x*hv.x + w_r[j].y*hv.y + w_r[j].z*hv.z + w_r[j].w*hv.w;
      az += w_z[j].x*hv.x + w_z[j].y*hv.y + w_z[j].z*hv.z + w_z[j].w*hv.w;
      an += w_n[j].x*hv.x + w_n[j].y*hv.y + w_n[j].z*hv.z + w_n[j].w*hv.w;
    }
    ar += __shfl_xor(ar,1); ar += __shfl_xor(ar,2);
    az += __shfl_xor(az,1); az += __shfl_xor(az,2);
    an += __shfl_xor(an,1); an += __shfl_xor(an,2);
    if (part==0){
      float rg = sigmoidf_(xr + ar + b_r);
      float zg = sigmoidf_(xz + az + b_z);
      float ng = tanh_fast(xn + rg*(an + b_n));
      float h2 = (1.f-zg)*ng + zg*hprev;
      hprev = h2;
      h[cur^1][r] = h2;
      out[((size_t)b*SS+s)*D2 + dir*EE + r] = h2;
      if (t+1<SS){
        int sn = dir? (SS-2-t) : (t+1);
        const float* gn = gx + ((size_t)b*SS+sn)*H3;
        xr=gn[r]; xz=gn[EE+r]; xn=gn[2*EE+r];
      }
    }
    cur^=1;
    __syncthreads();
  }
  if (hT && part==0) hT[((size_t)dir*BB+b)*EE+r]=hprev;
}

__global__ void k_copy_hq(const float* __restrict__ hq, float* __restrict__ agg){
  int row=blockIdx.x;
  agg[(size_t)row*D12 + threadIdx.x] = hq[(size_t)row*D2 + threadIdx.x];
}

// --------- block softmax over 256 values, p[tid] gets probability ---------
__device__ __forceinline__ void softmax256(float val, float* red, float* p){
  int tid=threadIdx.x;
  red[tid]=val; __syncthreads();
  for (int st=128; st>0; st>>=1){ if (tid<st) red[tid]=fmaxf(red[tid],red[tid+st]); __syncthreads(); }
  float mx=red[0]; __syncthreads();
  float ex=__expf(val-mx); red[tid]=ex; __syncthreads();
  for (int st=128; st>0; st>>=1){ if (tid<st) red[tid]+=red[tid+st]; __syncthreads(); }
  float inv=1.f/red[0];
  p[tid]=ex*inv; __syncthreads();
}

// ---------------- additive-style attention (ptc: sign=+1, ptm: sign=-1) ----------------
__global__ __launch_bounds__(256) void k_attn_add(const float* __restrict__ A, const float* __restrict__ Bq,
                          const float* __restrict__ v, float sign,
                          const float* __restrict__ V, float* __restrict__ aggout, int off){
  __shared__ __align__(16) float bq[EE];
  __shared__ __align__(16) float vv[EE];
  __shared__ float p[SS]; __shared__ float red[SS];
  int q=blockIdx.x, b=blockIdx.y, tid=threadIdx.x;
  if (tid<EE){ bq[tid]=sign*Bq[((size_t)b*SS+q)*EE+tid]; vv[tid]=v[tid]; }
  __syncthreads();
  const float* Ar = A + ((size_t)b*SS+tid)*EE;   // thread = key index k
  float s=0.f;
  #pragma unroll
  for (int e=0;e<EE;e+=4){
    float4 a=*(const float4*)(Ar+e);
    float4 bb=*(const float4*)(bq+e);
    float4 vw=*(const float4*)(vv+e);
    s += vw.x*tanh_fast(a.x+bb.x)+vw.y*tanh_fast(a.y+bb.y)+vw.z*tanh_fast(a.z+bb.z)+vw.w*tanh_fast(a.w+bb.w);
  }
  softmax256(s, red, p);
  const float* V0 = V + (size_t)b*SS*D2;
  float o=0.f;
  for (int k=0;k<SS;k++) o += p[k]*V0[(size_t)k*D2+tid];
  aggout[((size_t)b*SS+q)*D12 + off + tid] = o;
}

// ---------------- bilinear attention (ptb) ----------------
__global__ __launch_bounds__(256) void k_attn_bil(const float* __restrict__ Pb, const float* __restrict__ hq,
                          const float* __restrict__ V, float* __restrict__ aggout, int off){
  __shared__ __align__(16) float hqq[D2];
  __shared__ float p[SS]; __shared__ float red[SS];
  int q=blockIdx.x, b=blockIdx.y, tid=threadIdx.x;
  hqq[tid]=hq[((size_t)b*SS+q)*D2+tid];
  __syncthreads();
  const float* Pr = Pb + ((size_t)b*SS+tid)*D2;
  float s=0.f;
  #pragma unroll
  for (int d=0;d<D2;d+=4){
    float4 a=*(const float4*)(Pr+d);
    float4 hh=*(const float4*)(hqq+d);
    s += a.x*hh.x+a.y*hh.y+a.z*hh.z+a.w*hh.w;
  }
  softmax256(s, red, p);
  const float* V0 = V + (size_t)b*SS*D2;
  float o=0.f;
  for (int k=0;k<SS;k++) o += p[k]*V0[(size_t)k*D2+tid];
  aggout[((size_t)b*SS+q)*D12 + off + tid] = o;
}

// ------- fused ptd/pts: MFMA scores + tanh/v reduce + softmax + PV -------
// sc[k] = sum_e v[e] tanh( sum_d W[e,d] keys[k,d] qm[q,d] ),  out = softmax_k(sc) @ V
// Per block (q,b): A = keys (bf16) row-scaled by qm[q,:]; per-(b,q) matmul M=256(k) N=128(e) K=256(d)
// via mfma_f32_32x32x16_bf16. Wave w owns k-rows [w*64, w*64+64), all 128 e in 4 n-tiles.
__global__ __launch_bounds__(256, 2) void k_mulattn_fused(
    const unsigned short* __restrict__ keysb,  // [B][S][D2] bf16
    const float* __restrict__ qm,              // [B][S][D2] f32 (hq)
    const unsigned short* __restrict__ Wb,     // [E][D2] bf16
    const float* __restrict__ v,               // [E]
    const float* __restrict__ V,               // [B][S][D2] f32 (PV source)
    float* __restrict__ aggout, int off){
  __shared__ __align__(16) float qrow[D2];
  __shared__ __align__(16) float vrow[EE];
  __shared__ float scq[SS];
  __shared__ float red[SS];
  __shared__ float p[SS];
  int q=blockIdx.x, b=blockIdx.y, tid=threadIdx.x;
  int wave=tid>>6, lane=tid&63;
  size_t bS = (size_t)b*SS;
  qrow[tid]=qm[(bS+q)*D2+tid];
  if (tid<EE) vrow[tid]=v[tid];
  __syncthreads();

  f32x16 acc[2][4]={};
  int m0 = wave*64;
  int col = lane&31, half = lane>>5;
  const unsigned short* krow0 = keysb + (bS + m0 + col)*D2 + half*8;
  const unsigned short* krow1 = krow0 + 32*D2;
  const unsigned short* wrow[4];
  #pragma unroll
  for (int n=0;n<4;n++) wrow[n] = Wb + (size_t)(n*32+col)*D2 + half*8;

  for (int d0=0; d0<D2; d0+=16){
    // per-lane qm scale factors for this chunk (broadcast LDS reads)
    float4 qsA = *(const float4*)&qrow[d0 + half*8];
    float4 qsB = *(const float4*)&qrow[d0 + half*8 + 4];
    // B fragments: direct 16B bf16 loads, exact MFMA B-layout (n=lane&31, k=half*8+j)
    short8 bfrag[4];
    #pragma unroll
    for (int n=0;n<4;n++) bfrag[n] = __builtin_bit_cast(short8, *(const uint4*)(wrow[n]+d0));
    // A fragments: load 8 bf16, unpack, scale by qm, repack (RNE)
    #pragma unroll
    for (int i=0;i<2;i++){
      uint4 raw = *(const uint4*)((i? krow1:krow0) + d0);
      float f0=bf16_to_f(raw.x)*qsA.x, f1=bf16hi_to_f(raw.x)*qsA.y;
      float f2=bf16_to_f(raw.y)*qsA.z, f3=bf16hi_to_f(raw.y)*qsA.w;
      float f4=bf16_to_f(raw.z)*qsB.x, f5=bf16hi_to_f(raw.z)*qsB.y;
      float f6=bf16_to_f(raw.w)*qsB.z, f7=bf16hi_to_f(raw.w)*qsB.w;
      uint4 pk;
      pk.x=pack_bf16x2(f0,f1);
      pk.y=pack_bf16x2(f2,f3);
      pk.z=pack_bf16x2(f4,f5);
      pk.w=pack_bf16x2(f6,f7);
      short8 afrag = __builtin_bit_cast(short8, pk);
      #pragma unroll
      for (int n=0;n<4;n++)
        acc[i][n] = __builtin_amdgcn_mfma_f32_32x32x16_bf16(afrag, bfrag[n], acc[i][n], 0,0,0);
    }
  }
  // epilogue: sc[k] = sum_e v[e]*tanh(C[k,e]); C layout col=lane&31(e), row=(r&3)+8*(r>>2)+4*half
  float vn[4];
  #pragma unroll
  for (int n=0;n<4;n++) vn[n]=vrow[n*32+col];
  #pragma unroll
  for (int i=0;i<2;i++){
    #pragma unroll
    for (int r=0;r<16;r++){
      float s = vn[0]*tanh_fast(acc[i][0][r]) + vn[1]*tanh_fast(acc[i][1][r])
              + vn[2]*tanh_fast(acc[i][2][r]) + vn[3]*tanh_fast(acc[i][3][r]);
      s += __shfl_xor(s,1,32); s += __shfl_xor(s,2,32); s += __shfl_xor(s,4,32);
      s += __shfl_xor(s,8,32); s += __shfl_xor(s,16,32);
      int k = m0 + i*32 + (r&3) + 8*(r>>2) + 4*half;
      scq[k] = s;   // 32 lanes, same addr, same value
    }
  }
  __syncthreads();
  // softmax over 256 scores + PV
  float val = scq[tid];
  softmax256(val, red, p);
  const float* V0 = V + bS*D2;
  float o=0.f;
  for (int k=0;k<SS;k++) o += p[k]*V0[(size_t)k*D2+tid];
  aggout[(bS+q)*D12 + off + tid] = o;
}

// ---------------- rl pooling over hq ----------------
__global__ __launch_bounds__(256) void k_rl(const float* __restrict__ spj, const float* __restrict__ hq,
                    const float* __restrict__ vp, float* __restrict__ rl){
  __shared__ __align__(16) float vpl[EE];
  __shared__ float p[SS]; __shared__ float red[SS];
  int b=blockIdx.x, tid=threadIdx.x;
  if (tid<EE) vpl[tid]=vp[tid];
  __syncthreads();
  const float* row = spj + ((size_t)b*SS+tid)*EE;
  float sj=0.f;
  #pragma unroll
  for (int e=0;e<EE;e+=4){
    float4 a=*(const float4*)(row+e);
    float4 vw=*(const float4*)(vpl+e);
    sj += vw.x*tanh_fast(a.x)+vw.y*tanh_fast(a.y)+vw.z*tanh_fast(a.z)+vw.w*tanh_fast(a.w);
  }
  softmax256(sj, red, p);
  float o=0.f;
  for (int s=0;s<SS;s++) o += p[s]*hq[((size_t)b*SS+s)*D2+tid];
  rl[(size_t)b*D2+tid]=o;
}

// ---------------- final pooling + prediction ----------------
__global__ __launch_bounds__(256) void k_final(const float* __restrict__ sA, const float* __restrict__ sB,
                       const float* __restrict__ vc, const float* __restrict__ agg_rep,
                       const float* __restrict__ Wpred, float* __restrict__ out){
  __shared__ __align__(16) float sBl[EE];
  __shared__ __align__(16) float vcl[EE];
  __shared__ float p[SS]; __shared__ float red[SS]; __shared__ float rr[D2];
  int b=blockIdx.x, tid=threadIdx.x;
  if (tid<EE){ sBl[tid]=sB[(size_t)b*EE+tid]; vcl[tid]=vc[tid]; }
  __syncthreads();
  const float* rowA = sA + ((size_t)b*SS+tid)*EE;
  float sc=0.f;
  #pragma unroll
  for (int e=0;e<EE;e+=4){
    float4 a=*(const float4*)(rowA+e);
    float4 bb=*(const float4*)(sBl+e);
    float4 vw=*(const float4*)(vcl+e);
    sc += vw.x*(a.x+bb.x)+vw.y*(a.y+bb.y)+vw.z*(a.z+bb.z)+vw.w*(a.w+bb.w);   // note: no tanh
  }
  softmax256(sc, red, p);
  float o=0.f;
  for (int s=0;s<SS;s++) o += p[s]*agg_rep[((size_t)b*SS+s)*D2+tid];
  rr[tid]=o; __syncthreads();
  if (tid<LL){
    float a=0.f;
    const float* wr = Wpred + (size_t)tid*D2;
    for (int d=0;d<D2;d++) a += wr[d]*rr[d];
    out[(size_t)b*LL+tid]=sigmoidf_(a);
  }
}

extern "C" void kernel_launch(void* const* d_in, const int* in_sizes, int n_in,
                              void* d_out, int out_size, void* d_ws, size_t ws_size,
                              hipStream_t stream){
  (void)in_sizes; (void)n_in; (void)out_size; (void)ws_size;
  const int*   inp = (const int*)d_in[0];
  const float* emb = (const float*)d_in[1];
  const float* enc_wih_f=(const float*)d_in[2],  *enc_whh_f=(const float*)d_in[3],
             *enc_bih_f=(const float*)d_in[4],  *enc_bhh_f=(const float*)d_in[5];
  const float* enc_wih_b=(const float*)d_in[6],  *enc_whh_b=(const float*)d_in[7],
             *enc_bih_b=(const float*)d_in[8],  *enc_bhh_b=(const float*)d_in[9];
  const float* hid_wih_f=(const float*)d_in[10], *hid_whh_f=(const float*)d_in[11],
             *hid_bih_f=(const float*)d_in[12], *hid_bhh_f=(const float*)d_in[13];
  const float* hid_wih_b=(const float*)d_in[14], *hid_whh_b=(const float*)d_in[15],
             *hid_bih_b=(const float*)d_in[16], *hid_bhh_b=(const float*)d_in[17];
  const float* agg_wih_f=(const float*)d_in[18], *agg_whh_f=(const float*)d_in[19],
             *agg_bih_f=(const float*)d_in[20], *agg_bhh_f=(const float*)d_in[21];
  const float* agg_wih_b=(const float*)d_in[22], *agg_whh_b=(const float*)d_in[23],
             *agg_bih_b=(const float*)d_in[24], *agg_bhh_b=(const float*)d_in[25];
  const float* Wc1=(const float*)d_in[26], *Wc2=(const float*)d_in[27], *vc=(const float*)d_in[28];
  const float* Wb =(const float*)d_in[29];
  const float* Wd =(const float*)d_in[30], *vd=(const float*)d_in[31];
  const float* Wm =(const float*)d_in[32], *vm=(const float*)d_in[33];
  const float* Ws =(const float*)d_in[34], *vs=(const float*)d_in[35];
  const float* Wp =(const float*)d_in[36], *vp=(const float*)d_in[37];
  const float* Wpred=(const float*)d_in[38];

  float* ws = (float*)d_ws;
  size_t o = 0;
  float* x       = ws + o; o += (size_t)BB*SS*DD;
  float* gxf     = ws + o; o += (size_t)BB*SS*H3;
  float* gxb     = ws + o; o += (size_t)BB*SS*H3;
  float* hp      = ws + o; o += (size_t)BB*SS*D2;
  float* hq      = ws + o; o += (size_t)BB*SS*D2;
  float* hidden  = ws + o; o += (size_t)2*BB*EE;
  float* s1      = ws + o; o += (size_t)BB*SS*EE;
  float* s2      = ws + o; o += (size_t)BB*SS*EE;
  float* Am      = ws + o; o += (size_t)BB*SS*EE;
  float* Bm      = ws + o; o += (size_t)BB*SS*EE;
  float* Pb      = ws + o; o += (size_t)BB*SS*D2;
  float* spj     = ws + o; o += (size_t)BB*SS*EE;
  float* agg     = ws + o; o += (size_t)BB*SS*D12;
  float* agg_rep = ws + o; o += (size_t)BB*SS*D2;
  float* rl      = ws + o; o += (size_t)BB*D2;
  float* sA      = ws + o; o += (size_t)BB*SS*EE;
  float* sB      = ws + o; o += (size_t)BB*EE;
  unsigned short* hp_bf = (unsigned short*)(ws + o); o += (size_t)BB*SS*D2/2;
  unsigned short* hq_bf = (unsigned short*)(ws + o); o += (size_t)BB*SS*D2/2;
  unsigned short* Wd_bf = (unsigned short*)(ws + o); o += (size_t)EE*D2/2;
  unsigned short* Ws_bf = (unsigned short*)(ws + o); o += (size_t)EE*D2/2;

  auto mm=[&](const float* X,const float* W,const float* bias,float* outp,int M,int N,int K){
    dim3 g((N+63)/64,(M+63)/64);
    k_matmul<<<g,256,0,stream>>>(X,W,bias,outp,M,N,K);
  };

  k_embed<<<BB*SS,256,0,stream>>>(inp, emb, x);
  // weight bf16 copies (independent of data path)
  k_cvt_bf16<<<(EE*D2/2+255)/256,256,0,stream>>>(Wd, Wd_bf, EE*D2/2);
  k_cvt_bf16<<<(EE*D2/2+255)/256,256,0,stream>>>(Ws, Ws_bf, EE*D2/2);

  // encoder BiGRU
  mm(x, enc_wih_f, enc_bih_f, gxf, BB*SS, H3, DD);
  mm(x, enc_wih_b, enc_bih_b, gxb, BB*SS, H3, DD);
  k_gru_scan<<<dim3(BB,2),512,0,stream>>>(gxf,gxb,enc_whh_f,enc_whh_b,enc_bhh_f,enc_bhh_b,
                                          nullptr,hp,hidden);
  k_cvt_bf16<<<(BB*SS*D2/2+255)/256,256,0,stream>>>(hp, hp_bf, BB*SS*D2/2);
  // hidden BiGRU
  mm(hp, hid_wih_f, hid_bih_f, gxf, BB*SS, H3, D2);
  mm(hp, hid_wih_b, hid_bih_b, gxb, BB*SS, H3, D2);
  k_gru_scan<<<dim3(BB,2),512,0,stream>>>(gxf,gxb,hid_whh_f,hid_whh_b,hid_bhh_f,hid_bhh_b,
                                          hidden,hq,nullptr);
  k_cvt_bf16<<<(BB*SS*D2/2+255)/256,256,0,stream>>>(hq, hq_bf, BB*SS*D2/2);
  // projections
  mm(hp, Wc1, nullptr, s1,  BB*SS, EE, D2);
  mm(hq, Wc2, nullptr, s2,  BB*SS, EE, D2);
  mm(hp, Wm,  nullptr, Am,  BB*SS, EE, D2);
  mm(hq, Wm,  nullptr, Bm,  BB*SS, EE, D2);
  mm(hp, Wb,  nullptr, Pb,  BB*SS, D2, D2);
  mm(hq, Wp,  nullptr, spj, BB*SS, EE, D2);

  // agg slices: hq(0) pts(256) ptc(512) ptd(768) ptb(1024) ptm(1280)
  k_copy_hq<<<BB*SS,256,0,stream>>>(hq, agg);
  dim3 gq(SS,BB);
  k_attn_add<<<gq,256,0,stream>>>(s1,s2,vc, 1.f, hp, agg, 512);   // ptc
  k_attn_add<<<gq,256,0,stream>>>(Am,Bm,vm,-1.f, hp, agg, 1280);  // ptm (separable)
  k_attn_bil<<<gq,256,0,stream>>>(Pb,hq,hp,agg,1024);             // ptb
  k_mulattn_fused<<<gq,256,0,stream>>>(hp_bf,hq,Wd_bf,vd,hp,agg,768);  // ptd
  k_mulattn_fused<<<gq,256,0,stream>>>(hq_bf,hq,Ws_bf,vs,hq,agg,256);  // pts

  // aggregation BiGRU
  mm(agg, agg_wih_f, agg_bih_f, gxf, BB*SS, H3, D12);
  mm(agg, agg_wih_b, agg_bih_b, gxb, BB*SS, H3, D12);
  k_gru_scan<<<dim3(BB,2),512,0,stream>>>(gxf,gxb,agg_whh_f,agg_whh_b,agg_bhh_f,agg_bhh_b,
                                          nullptr,agg_rep,nullptr);

  // pooling + prediction
  k_rl<<<BB,256,0,stream>>>(spj,hq,vp,rl);
  mm(agg_rep, Wc1, nullptr, sA, BB*SS, EE, D2);
  mm(rl,      Wc2, nullptr, sB, BB,    EE, D2);
  k_final<<<BB,256,0,stream>>>(sA,sB,vc,agg_rep,Wpred,(float*)d_out);
}

// Round 5
// 1180.412 us; speedup vs baseline: 2.2015x; 1.5721x over previous
//
#include <hip/hip_runtime.h>
#include <math.h>

#define BB 4
#define SS 256
#define DD 300
#define DP 304   // DD padded to multiple of 16
#define EE 128
#define LL 20
#define H3 384
#define D2 256   // 2E
#define D12 1536 // 12E

typedef __attribute__((ext_vector_type(8)))  short short8;
typedef __attribute__((ext_vector_type(16))) float f32x16;

__device__ __forceinline__ float tanh_fast(float x){
  float e = __expf(2.f*x);
  return 1.f - 2.f/(e+1.f);
}
__device__ __forceinline__ float sigmoidf_(float x){ return 1.f/(1.f+__expf(-x)); }
__device__ __forceinline__ float bf16_to_f(unsigned u){ return __builtin_bit_cast(float, u<<16); }
__device__ __forceinline__ float bf16hi_to_f(unsigned u){ return __builtin_bit_cast(float, u & 0xFFFF0000u); }
__device__ __forceinline__ unsigned bf16_rne(float f){
  unsigned u = __builtin_bit_cast(unsigned, f);
  return (u + 0x7FFFu + ((u>>16)&1u)) >> 16;
}
__device__ __forceinline__ unsigned pack_bf16x2(float lo, float hi){
  return bf16_rne(lo) | (bf16_rne(hi)<<16);
}

// ---------------- f32 -> bf16 (RNE), 2 elems/thread ----------------
__global__ void k_cvt_bf16(const float* __restrict__ src, unsigned short* __restrict__ dst, int n2){
  int i = blockIdx.x*blockDim.x + threadIdx.x;
  if (i < n2){
    float2 f = *(const float2*)(src + 2*i);
    *(unsigned*)(dst + 2*i) = pack_bf16x2(f.x, f.y);
  }
}

// ---------------- fused weight conversion (13 segments, K-padding aware) ----------------
struct CvtSeg { const float* src; unsigned short* dst; int rows, Ks, Kd; };
struct CvtArgs { CvtSeg s[13]; };
__global__ void k_cvt_weights(CvtArgs a){
  CvtSeg sg = a.s[blockIdx.y];
  int p = blockIdx.x*256 + threadIdx.x;          // dst pair index
  int Kd2 = sg.Kd>>1;
  int npairs = sg.rows*Kd2;
  if (p >= npairs) return;
  int row = p/Kd2, kk = (p - row*Kd2)*2;
  float f0 = (kk   < sg.Ks)? sg.src[(size_t)row*sg.Ks+kk  ] : 0.f;
  float f1 = (kk+1 < sg.Ks)? sg.src[(size_t)row*sg.Ks+kk+1] : 0.f;
  *(unsigned*)(sg.dst + (size_t)row*sg.Kd + kk) = pack_bf16x2(f0,f1);
}

// ---------------- embedding gather -> padded bf16 ----------------
__global__ void k_embed(const int* __restrict__ inp, const float* __restrict__ emb,
                        unsigned short* __restrict__ xb){
  int row = blockIdx.x;            // b*S+s
  int idx = inp[row];
  const float* src = emb + (size_t)idx*DD;
  unsigned short* dst = xb + (size_t)row*DP;
  int p = threadIdx.x;             // pair index, 152 pairs
  if (p < DP/2){
    float f0 = (2*p   < DD)? src[2*p  ] : 0.f;
    float f1 = (2*p+1 < DD)? src[2*p+1] : 0.f;
    *(unsigned*)(dst + 2*p) = pack_bf16x2(f0,f1);
  }
}

// ---------------- init gx pair with input-projection biases ----------------
__global__ void k_init2(float* __restrict__ gf, const float* __restrict__ bf,
                        float* __restrict__ gb, const float* __restrict__ bb){
  int row = blockIdx.x, n = threadIdx.x;   // block = H3 threads
  gf[(size_t)row*H3+n] = bf[n];
  gb[(size_t)row*H3+n] = bb[n];
}

// ---------------- bf16 MFMA matmul: out[M,N] (+)= X[M,K] @ W[N,K]^T ----------------
// 1 wave/block, wave tile 64m x 32n, direct-from-global fragments (no LDS, no barriers).
// gridDim.z>1: split-K, atomicAdd into pre-initialized out. gridDim.z==1: plain store (+bias).
__global__ __launch_bounds__(64) void k_mmbf(
    const unsigned short* __restrict__ X, const unsigned short* __restrict__ W,
    const float* __restrict__ bias, float* __restrict__ out,
    int N, int K, int kspan){
  int lane=threadIdx.x, col=lane&31, half=lane>>5;
  int n0=blockIdx.x*32, m0=blockIdx.y*64;
  int ks=blockIdx.z*kspan, ke=ks+kspan; if (ke>K) ke=K;
  const unsigned short* pa0 = X + (size_t)(m0+col)*K + half*8;
  const unsigned short* pa1 = pa0 + (size_t)32*K;
  const unsigned short* pb  = W + (size_t)(n0+col)*K + half*8;
  f32x16 acc0={}, acc1={};
  #pragma unroll 2
  for (int k=ks;k<ke;k+=16){
    short8 a0=__builtin_bit_cast(short8, *(const uint4*)(pa0+k));
    short8 a1=__builtin_bit_cast(short8, *(const uint4*)(pa1+k));
    short8 bv=__builtin_bit_cast(short8, *(const uint4*)(pb +k));
    acc0=__builtin_amdgcn_mfma_f32_32x32x16_bf16(a0,bv,acc0,0,0,0);
    acc1=__builtin_amdgcn_mfma_f32_32x32x16_bf16(a1,bv,acc1,0,0,0);
  }
  int cn = n0+col;
  if (gridDim.z==1){
    float bn = bias? bias[cn] : 0.f;
    #pragma unroll
    for (int r=0;r<16;r++){
      int row=(r&3)+8*(r>>2)+4*half;
      out[(size_t)(m0+row)*N+cn]    = acc0[r]+bn;
      out[(size_t)(m0+32+row)*N+cn] = acc1[r]+bn;
    }
  } else {
    #pragma unroll
    for (int r=0;r<16;r++){
      int row=(r&3)+8*(r>>2)+4*half;
      atomicAdd(&out[(size_t)(m0+row)*N+cn],    acc0[r]);
      atomicAdd(&out[(size_t)(m0+32+row)*N+cn], acc1[r]);
    }
  }
}

// ---------------- GRU scan (one block per (batch, direction)) ----------------
__global__ __launch_bounds__(512, 2) void k_gru_scan(const float* __restrict__ gxf, const float* __restrict__ gxb,
                          const float* __restrict__ whhf, const float* __restrict__ whhb,
                          const float* __restrict__ bhhf, const float* __restrict__ bhhb,
                          const float* __restrict__ h0,
                          float* __restrict__ out,
                          float* __restrict__ hT){
  int b=blockIdx.x, dir=blockIdx.y, tid=threadIdx.x;
  const float* gx  = dir? gxb : gxf;
  const float* whh = dir? whhb : whhf;
  const float* bhh = dir? bhhb : bhhf;
  int r = tid>>2, part = tid&3, phase = r&7;
  float4 w_r[8], w_z[8], w_n[8];
  #pragma unroll
  for (int j=0;j<8;j++){
    int jj=(j+phase)&7;
    int off = part*32 + jj*4;
    w_r[j] = *(const float4*)&whh[(size_t)r*EE        + off];
    w_z[j] = *(const float4*)&whh[(size_t)(r+128)*EE  + off];
    w_n[j] = *(const float4*)&whh[(size_t)(r+256)*EE  + off];
  }
  float b_r=bhh[r], b_z=bhh[r+128], b_n=bhh[r+256];
  __shared__ __align__(16) float h[2][EE];
  float hprev = h0? h0[((size_t)dir*BB+b)*EE + r] : 0.f;
  if (part==0) h[0][r] = hprev;
  float xr=0.f,xz=0.f,xn=0.f;
  {
    int s0 = dir? (SS-1) : 0;
    const float* g0 = gx + ((size_t)b*SS+s0)*H3;
    if (part==0){ xr=g0[r]; xz=g0[EE+r]; xn=g0[2*EE+r]; }
  }
  __syncthreads();
  int cur=0;
  for (int t=0;t<SS;t++){
    int s = dir? (SS-1-t) : t;
    float ar=0.f, az=0.f, an=0.f;
    #pragma unroll
    for (int j=0;j<8;j++){
      int jj=(j+phase)&7;
      float4 hv = *(const float4*)&h[cur][part*32 + jj*4];
      ar += w_r[j].x*hv.x + w_r[j].y*hv.y + w_r[j].z*hv.z + w_r[j].w*hv.w;
      az += w_z[j].x*hv.x + w_z[j].y*hv.y + w_z[j].z*hv.z + w_z[j].w*hv.w;
      an += w_n[j].x*hv.x + w_n[j].y*hv.y + w_n[j].z*hv.z + w_n[j].w*hv.w;
    }
    ar += __shfl_xor(ar,1); ar += __shfl_xor(ar,2);
    az += __shfl_xor(az,1); az += __shfl_xor(az,2);
    an += __shfl_xor(an,1); an += __shfl_xor(an,2);
    if (part==0){
      float rg = sigmoidf_(xr + ar + b_r);
      float zg = sigmoidf_(xz + az + b_z);
      float ng = tanh_fast(xn + rg*(an + b_n));
      float h2 = (1.f-zg)*ng + zg*hprev;
      hprev = h2;
      h[cur^1][r] = h2;
      out[((size_t)b*SS+s)*D2 + dir*EE + r] = h2;
      if (t+1<SS){
        int sn = dir? (SS-2-t) : (t+1);
        const float* gn = gx + ((size_t)b*SS+sn)*H3;
        xr=gn[r]; xz=gn[EE+r]; xn=gn[2*EE+r];
      }
    }
    cur^=1;
    __syncthreads();
  }
  if (hT && part==0) hT[((size_t)dir*BB+b)*EE+r]=hprev;
}

__global__ void k_copy_hq(const unsigned short* __restrict__ hqb, unsigned short* __restrict__ aggb){
  int row=blockIdx.x;
  aggb[(size_t)row*D12 + threadIdx.x] = hqb[(size_t)row*D2 + threadIdx.x];
}

// --------- block softmax over 256 values ---------
__device__ __forceinline__ void softmax256(float val, float* red, float* p){
  int tid=threadIdx.x;
  red[tid]=val; __syncthreads();
  for (int st=128; st>0; st>>=1){ if (tid<st) red[tid]=fmaxf(red[tid],red[tid+st]); __syncthreads(); }
  float mx=red[0]; __syncthreads();
  float ex=__expf(val-mx); red[tid]=ex; __syncthreads();
  for (int st=128; st>0; st>>=1){ if (tid<st) red[tid]+=red[tid+st]; __syncthreads(); }
  float inv=1.f/red[0];
  p[tid]=ex*inv; __syncthreads();
}

// ---------------- additive-style attention (ptc: +1, ptm: -1), bf16 out ----------------
__global__ __launch_bounds__(256) void k_attn_add(const float* __restrict__ A, const float* __restrict__ Bq,
                          const float* __restrict__ v, float sign,
                          const float* __restrict__ V, unsigned short* __restrict__ aggout, int off){
  __shared__ __align__(16) float bq[EE];
  __shared__ __align__(16) float vv[EE];
  __shared__ float p[SS]; __shared__ float red[SS];
  int q=blockIdx.x, b=blockIdx.y, tid=threadIdx.x;
  if (tid<EE){ bq[tid]=sign*Bq[((size_t)b*SS+q)*EE+tid]; vv[tid]=v[tid]; }
  __syncthreads();
  const float* Ar = A + ((size_t)b*SS+tid)*EE;
  float s=0.f;
  #pragma unroll
  for (int e=0;e<EE;e+=4){
    float4 a=*(const float4*)(Ar+e);
    float4 bb=*(const float4*)(bq+e);
    float4 vw=*(const float4*)(vv+e);
    s += vw.x*tanh_fast(a.x+bb.x)+vw.y*tanh_fast(a.y+bb.y)+vw.z*tanh_fast(a.z+bb.z)+vw.w*tanh_fast(a.w+bb.w);
  }
  softmax256(s, red, p);
  const float* V0 = V + (size_t)b*SS*D2;
  float o=0.f;
  for (int k=0;k<SS;k++) o += p[k]*V0[(size_t)k*D2+tid];
  aggout[((size_t)b*SS+q)*D12 + off + tid] = (unsigned short)bf16_rne(o);
}

// ---------------- bilinear attention (ptb), bf16 out ----------------
__global__ __launch_bounds__(256) void k_attn_bil(const float* __restrict__ Pb, const float* __restrict__ hq,
                          const float* __restrict__ V, unsigned short* __restrict__ aggout, int off){
  __shared__ __align__(16) float hqq[D2];
  __shared__ float p[SS]; __shared__ float red[SS];
  int q=blockIdx.x, b=blockIdx.y, tid=threadIdx.x;
  hqq[tid]=hq[((size_t)b*SS+q)*D2+tid];
  __syncthreads();
  const float* Pr = Pb + ((size_t)b*SS+tid)*D2;
  float s=0.f;
  #pragma unroll
  for (int d=0;d<D2;d+=4){
    float4 a=*(const float4*)(Pr+d);
    float4 hh=*(const float4*)(hqq+d);
    s += a.x*hh.x+a.y*hh.y+a.z*hh.z+a.w*hh.w;
  }
  softmax256(s, red, p);
  const float* V0 = V + (size_t)b*SS*D2;
  float o=0.f;
  for (int k=0;k<SS;k++) o += p[k]*V0[(size_t)k*D2+tid];
  aggout[((size_t)b*SS+q)*D12 + off + tid] = (unsigned short)bf16_rne(o);
}

// ------- fused ptd/pts: MFMA scores + tanh/v reduce + softmax + PV, bf16 out -------
__global__ __launch_bounds__(256, 2) void k_mulattn_fused(
    const unsigned short* __restrict__ keysb,
    const float* __restrict__ qm,
    const unsigned short* __restrict__ Wb,
    const float* __restrict__ v,
    const float* __restrict__ V,
    unsigned short* __restrict__ aggout, int off){
  __shared__ __align__(16) float qrow[D2];
  __shared__ __align__(16) float vrow[EE];
  __shared__ float scq[SS];
  __shared__ float red[SS];
  __shared__ float p[SS];
  int q=blockIdx.x, b=blockIdx.y, tid=threadIdx.x;
  int wave=tid>>6, lane=tid&63;
  size_t bS = (size_t)b*SS;
  qrow[tid]=qm[(bS+q)*D2+tid];
  if (tid<EE) vrow[tid]=v[tid];
  __syncthreads();

  f32x16 acc[2][4]={};
  int m0 = wave*64;
  int col = lane&31, half = lane>>5;
  const unsigned short* krow0 = keysb + (bS + m0 + col)*D2 + half*8;
  const unsigned short* krow1 = krow0 + 32*D2;
  const unsigned short* wrow[4];
  #pragma unroll
  for (int n=0;n<4;n++) wrow[n] = Wb + (size_t)(n*32+col)*D2 + half*8;

  for (int d0=0; d0<D2; d0+=16){
    float4 qsA = *(const float4*)&qrow[d0 + half*8];
    float4 qsB = *(const float4*)&qrow[d0 + half*8 + 4];
    short8 bfrag[4];
    #pragma unroll
    for (int n=0;n<4;n++) bfrag[n] = __builtin_bit_cast(short8, *(const uint4*)(wrow[n]+d0));
    #pragma unroll
    for (int i=0;i<2;i++){
      uint4 raw = *(const uint4*)((i? krow1:krow0) + d0);
      float f0=bf16_to_f(raw.x)*qsA.x, f1=bf16hi_to_f(raw.x)*qsA.y;
      float f2=bf16_to_f(raw.y)*qsA.z, f3=bf16hi_to_f(raw.y)*qsA.w;
      float f4=bf16_to_f(raw.z)*qsB.x, f5=bf16hi_to_f(raw.z)*qsB.y;
      float f6=bf16_to_f(raw.w)*qsB.z, f7=bf16hi_to_f(raw.w)*qsB.w;
      uint4 pk;
      pk.x=pack_bf16x2(f0,f1);
      pk.y=pack_bf16x2(f2,f3);
      pk.z=pack_bf16x2(f4,f5);
      pk.w=pack_bf16x2(f6,f7);
      short8 afrag = __builtin_bit_cast(short8, pk);
      #pragma unroll
      for (int n=0;n<4;n++)
        acc[i][n] = __builtin_amdgcn_mfma_f32_32x32x16_bf16(afrag, bfrag[n], acc[i][n], 0,0,0);
    }
  }
  float vn[4];
  #pragma unroll
  for (int n=0;n<4;n++) vn[n]=vrow[n*32+col];
  #pragma unroll
  for (int i=0;i<2;i++){
    #pragma unroll
    for (int r=0;r<16;r++){
      float s = vn[0]*tanh_fast(acc[i][0][r]) + vn[1]*tanh_fast(acc[i][1][r])
              + vn[2]*tanh_fast(acc[i][2][r]) + vn[3]*tanh_fast(acc[i][3][r]);
      s += __shfl_xor(s,1,32); s += __shfl_xor(s,2,32); s += __shfl_xor(s,4,32);
      s += __shfl_xor(s,8,32); s += __shfl_xor(s,16,32);
      int k = m0 + i*32 + (r&3) + 8*(r>>2) + 4*half;
      scq[k] = s;
    }
  }
  __syncthreads();
  float val = scq[tid];
  softmax256(val, red, p);
  const float* V0 = V + bS*D2;
  float o=0.f;
  for (int k=0;k<SS;k++) o += p[k]*V0[(size_t)k*D2+tid];
  aggout[(bS+q)*D12 + off + tid] = (unsigned short)bf16_rne(o);
}

// ---------------- rl pooling over hq + folded sB = rl @ Wc2^T ----------------
__global__ __launch_bounds__(256) void k_rl(const float* __restrict__ spj, const float* __restrict__ hq,
                    const float* __restrict__ vp, const float* __restrict__ Wc2,
                    float* __restrict__ sB){
  __shared__ __align__(16) float vpl[EE];
  __shared__ float p[SS]; __shared__ float red[SS];
  __shared__ __align__(16) float rr[D2];
  int b=blockIdx.x, tid=threadIdx.x;
  if (tid<EE) vpl[tid]=vp[tid];
  __syncthreads();
  const float* row = spj + ((size_t)b*SS+tid)*EE;
  float sj=0.f;
  #pragma unroll
  for (int e=0;e<EE;e+=4){
    float4 a=*(const float4*)(row+e);
    float4 vw=*(const float4*)(vpl+e);
    sj += vw.x*tanh_fast(a.x)+vw.y*tanh_fast(a.y)+vw.z*tanh_fast(a.z)+vw.w*tanh_fast(a.w);
  }
  softmax256(sj, red, p);
  float o=0.f;
  for (int s=0;s<SS;s++) o += p[s]*hq[((size_t)b*SS+s)*D2+tid];
  rr[tid]=o; __syncthreads();
  if (tid<EE){
    const float* wr = Wc2 + (size_t)tid*D2;
    float a=0.f;
    #pragma unroll
    for (int d=0;d<D2;d+=4){
      float4 w4=*(const float4*)(wr+d);
      float4 r4=*(const float4*)(rr+d);
      a += w4.x*r4.x+w4.y*r4.y+w4.z*r4.z+w4.w*r4.w;
    }
    sB[(size_t)b*EE+tid]=a;
  }
}

// ---------------- final pooling + prediction ----------------
__global__ __launch_bounds__(256) void k_final(const float* __restrict__ sA, const float* __restrict__ sB,
                       const float* __restrict__ vc, const float* __restrict__ agg_rep,
                       const float* __restrict__ Wpred, float* __restrict__ out){
  __shared__ __align__(16) float sBl[EE];
  __shared__ __align__(16) float vcl[EE];
  __shared__ float p[SS]; __shared__ float red[SS]; __shared__ float rr[D2];
  int b=blockIdx.x, tid=threadIdx.x;
  if (tid<EE){ sBl[tid]=sB[(size_t)b*EE+tid]; vcl[tid]=vc[tid]; }
  __syncthreads();
  const float* rowA = sA + ((size_t)b*SS+tid)*EE;
  float sc=0.f;
  #pragma unroll
  for (int e=0;e<EE;e+=4){
    float4 a=*(const float4*)(rowA+e);
    float4 bb=*(const float4*)(sBl+e);
    float4 vw=*(const float4*)(vcl+e);
    sc += vw.x*(a.x+bb.x)+vw.y*(a.y+bb.y)+vw.z*(a.z+bb.z)+vw.w*(a.w+bb.w);
  }
  softmax256(sc, red, p);
  float o=0.f;
  for (int s=0;s<SS;s++) o += p[s]*agg_rep[((size_t)b*SS+s)*D2+tid];
  rr[tid]=o; __syncthreads();
  if (tid<LL){
    float a=0.f;
    const float* wr = Wpred + (size_t)tid*D2;
    for (int d=0;d<D2;d++) a += wr[d]*rr[d];
    out[(size_t)b*LL+tid]=sigmoidf_(a);
  }
}

extern "C" void kernel_launch(void* const* d_in, const int* in_sizes, int n_in,
                              void* d_out, int out_size, void* d_ws, size_t ws_size,
                              hipStream_t stream){
  (void)in_sizes; (void)n_in; (void)out_size; (void)ws_size;
  const int*   inp = (const int*)d_in[0];
  const float* emb = (const float*)d_in[1];
  const float* enc_wih_f=(const float*)d_in[2],  *enc_whh_f=(const float*)d_in[3],
             *enc_bih_f=(const float*)d_in[4],  *enc_bhh_f=(const float*)d_in[5];
  const float* enc_wih_b=(const float*)d_in[6],  *enc_whh_b=(const float*)d_in[7],
             *enc_bih_b=(const float*)d_in[8],  *enc_bhh_b=(const float*)d_in[9];
  const float* hid_wih_f=(const float*)d_in[10], *hid_whh_f=(const float*)d_in[11],
             *hid_bih_f=(const float*)d_in[12], *hid_bhh_f=(const float*)d_in[13];
  const float* hid_wih_b=(const float*)d_in[14], *hid_whh_b=(const float*)d_in[15],
             *hid_bih_b=(const float*)d_in[16], *hid_bhh_b=(const float*)d_in[17];
  const float* agg_wih_f=(const float*)d_in[18], *agg_whh_f=(const float*)d_in[19],
             *agg_bih_f=(const float*)d_in[20], *agg_bhh_f=(const float*)d_in[21];
  const float* agg_wih_b=(const float*)d_in[22], *agg_whh_b=(const float*)d_in[23],
             *agg_bih_b=(const float*)d_in[24], *agg_bhh_b=(const float*)d_in[25];
  const float* Wc1=(const float*)d_in[26], *Wc2=(const float*)d_in[27], *vc=(const float*)d_in[28];
  const float* Wb =(const float*)d_in[29];
  const float* Wd =(const float*)d_in[30], *vd=(const float*)d_in[31];
  const float* Wm =(const float*)d_in[32], *vm=(const float*)d_in[33];
  const float* Ws =(const float*)d_in[34], *vs=(const float*)d_in[35];
  const float* Wp =(const float*)d_in[36], *vp=(const float*)d_in[37];
  const float* Wpred=(const float*)d_in[38];

  float* ws = (float*)d_ws;
  size_t o = 0;
  float* gxf     = ws + o; o += (size_t)BB*SS*H3;
  float* gxb     = ws + o; o += (size_t)BB*SS*H3;
  float* hp      = ws + o; o += (size_t)BB*SS*D2;
  float* hq      = ws + o; o += (size_t)BB*SS*D2;
  float* hidden  = ws + o; o += (size_t)2*BB*EE;
  float* s1      = ws + o; o += (size_t)BB*SS*EE;
  float* s2      = ws + o; o += (size_t)BB*SS*EE;
  float* Am      = ws + o; o += (size_t)BB*SS*EE;
  float* Bm      = ws + o; o += (size_t)BB*SS*EE;
  float* Pb      = ws + o; o += (size_t)BB*SS*D2;
  float* spj     = ws + o; o += (size_t)BB*SS*EE;
  float* agg_rep = ws + o; o += (size_t)BB*SS*D2;
  float* sA      = ws + o; o += (size_t)BB*SS*EE;
  float* sB      = ws + o; o += (size_t)BB*EE;
  // bf16 buffers (ushort counts, all even -> advance o by count/2)
  unsigned short* x_bf      = (unsigned short*)(ws+o); o += (size_t)BB*SS*DP/2;
  unsigned short* hp_bf     = (unsigned short*)(ws+o); o += (size_t)BB*SS*D2/2;
  unsigned short* hq_bf     = (unsigned short*)(ws+o); o += (size_t)BB*SS*D2/2;
  unsigned short* agg_bf    = (unsigned short*)(ws+o); o += (size_t)BB*SS*D12/2;
  unsigned short* aggrep_bf = (unsigned short*)(ws+o); o += (size_t)BB*SS*D2/2;
  unsigned short* encf_bf   = (unsigned short*)(ws+o); o += (size_t)H3*DP/2;
  unsigned short* encb_bf   = (unsigned short*)(ws+o); o += (size_t)H3*DP/2;
  unsigned short* hidf_bf   = (unsigned short*)(ws+o); o += (size_t)H3*D2/2;
  unsigned short* hidb_bf   = (unsigned short*)(ws+o); o += (size_t)H3*D2/2;
  unsigned short* aggf_bf   = (unsigned short*)(ws+o); o += (size_t)H3*D12/2;
  unsigned short* aggb_bf   = (unsigned short*)(ws+o); o += (size_t)H3*D12/2;
  unsigned short* Wc1_bf    = (unsigned short*)(ws+o); o += (size_t)EE*D2/2;
  unsigned short* Wc2_bf    = (unsigned short*)(ws+o); o += (size_t)EE*D2/2;
  unsigned short* Wm_bf     = (unsigned short*)(ws+o); o += (size_t)EE*D2/2;
  unsigned short* Wb_bf     = (unsigned short*)(ws+o); o += (size_t)D2*D2/2;
  unsigned short* Wp_bf     = (unsigned short*)(ws+o); o += (size_t)EE*D2/2;
  unsigned short* Wd_bf     = (unsigned short*)(ws+o); o += (size_t)EE*D2/2;
  unsigned short* Ws_bf     = (unsigned short*)(ws+o); o += (size_t)EE*D2/2;

  const int M = BB*SS; // 1024
  auto mmbf=[&](const unsigned short* X,const unsigned short* W,const float* bias,
                float* outp,int N,int K,int z,int kspan){
    dim3 g(N/32, M/64, z);
    k_mmbf<<<g,64,0,stream>>>(X,W,bias,outp,N,K,kspan);
  };

  // ---- input prep ----
  k_embed<<<M,256,0,stream>>>(inp, emb, x_bf);
  CvtArgs ca;
  ca.s[0]  = {enc_wih_f, encf_bf, H3, DD, DP};
  ca.s[1]  = {enc_wih_b, encb_bf, H3, DD, DP};
  ca.s[2]  = {hid_wih_f, hidf_bf, H3, D2, D2};
  ca.s[3]  = {hid_wih_b, hidb_bf, H3, D2, D2};
  ca.s[4]  = {agg_wih_f, aggf_bf, H3, D12, D12};
  ca.s[5]  = {agg_wih_b, aggb_bf, H3, D12, D12};
  ca.s[6]  = {Wc1, Wc1_bf, EE, D2, D2};
  ca.s[7]  = {Wc2, Wc2_bf, EE, D2, D2};
  ca.s[8]  = {Wm,  Wm_bf,  EE, D2, D2};
  ca.s[9]  = {Wb,  Wb_bf,  D2, D2, D2};
  ca.s[10] = {Wp,  Wp_bf,  EE, D2, D2};
  ca.s[11] = {Wd,  Wd_bf,  EE, D2, D2};
  ca.s[12] = {Ws,  Ws_bf,  EE, D2, D2};
  {
    int maxpairs = H3*D12/2;  // 294912
    dim3 g((maxpairs+255)/256, 13);
    k_cvt_weights<<<g,256,0,stream>>>(ca);
  }

  // ---- encoder BiGRU ----
  k_init2<<<M,H3,0,stream>>>(gxf, enc_bih_f, gxb, enc_bih_b);
  mmbf(x_bf, encf_bf, nullptr, gxf, H3, DP, 4, 80);
  mmbf(x_bf, encb_bf, nullptr, gxb, H3, DP, 4, 80);
  k_gru_scan<<<dim3(BB,2),512,0,stream>>>(gxf,gxb,enc_whh_f,enc_whh_b,enc_bhh_f,enc_bhh_b,
                                          nullptr,hp,hidden);
  k_cvt_bf16<<<(M*D2/2+255)/256,256,0,stream>>>(hp, hp_bf, M*D2/2);

  // ---- hidden BiGRU ----
  k_init2<<<M,H3,0,stream>>>(gxf, hid_bih_f, gxb, hid_bih_b);
  mmbf(hp_bf, hidf_bf, nullptr, gxf, H3, D2, 4, 64);
  mmbf(hp_bf, hidb_bf, nullptr, gxb, H3, D2, 4, 64);
  k_gru_scan<<<dim3(BB,2),512,0,stream>>>(gxf,gxb,hid_whh_f,hid_whh_b,hid_bhh_f,hid_bhh_b,
                                          hidden,hq,nullptr);
  k_cvt_bf16<<<(M*D2/2+255)/256,256,0,stream>>>(hq, hq_bf, M*D2/2);

  // ---- projections (ksplit=1, direct store) ----
  mmbf(hp_bf, Wc1_bf, nullptr, s1,  EE, D2, 1, D2);
  mmbf(hq_bf, Wc2_bf, nullptr, s2,  EE, D2, 1, D2);
  mmbf(hp_bf, Wm_bf,  nullptr, Am,  EE, D2, 1, D2);
  mmbf(hq_bf, Wm_bf,  nullptr, Bm,  EE, D2, 1, D2);
  mmbf(hp_bf, Wb_bf,  nullptr, Pb,  D2, D2, 1, D2);
  mmbf(hq_bf, Wp_bf,  nullptr, spj, EE, D2, 1, D2);

  // ---- attentions -> agg (bf16). slices: hq(0) pts(256) ptc(512) ptd(768) ptb(1024) ptm(1280)
  k_copy_hq<<<M,256,0,stream>>>(hq_bf, agg_bf);
  dim3 gq(SS,BB);
  k_attn_add<<<gq,256,0,stream>>>(s1,s2,vc, 1.f, hp, agg_bf, 512);
  k_attn_add<<<gq,256,0,stream>>>(Am,Bm,vm,-1.f, hp, agg_bf, 1280);
  k_attn_bil<<<gq,256,0,stream>>>(Pb,hq,hp,agg_bf,1024);
  k_mulattn_fused<<<gq,256,0,stream>>>(hp_bf,hq,Wd_bf,vd,hp,agg_bf,768);
  k_mulattn_fused<<<gq,256,0,stream>>>(hq_bf,hq,Ws_bf,vs,hq,agg_bf,256);

  // ---- aggregation BiGRU ----
  k_init2<<<M,H3,0,stream>>>(gxf, agg_bih_f, gxb, agg_bih_b);
  mmbf(agg_bf, aggf_bf, nullptr, gxf, H3, D12, 8, 192);
  mmbf(agg_bf, aggb_bf, nullptr, gxb, H3, D12, 8, 192);
  k_gru_scan<<<dim3(BB,2),512,0,stream>>>(gxf,gxb,agg_whh_f,agg_whh_b,agg_bhh_f,agg_bhh_b,
                                          nullptr,agg_rep,nullptr);
  k_cvt_bf16<<<(M*D2/2+255)/256,256,0,stream>>>(agg_rep, aggrep_bf, M*D2/2);

  // ---- pooling + prediction ----
  k_rl<<<BB,256,0,stream>>>(spj,hq,vp,Wc2,sB);
  mmbf(aggrep_bf, Wc1_bf, nullptr, sA, EE, D2, 1, D2);
  k_final<<<BB,256,0,stream>>>(sA,sB,vc,agg_rep,Wpred,(float*)d_out);
}